// Round 8
// baseline (294.467 us; speedup 1.0000x reference)
//
#include <hip/hip_runtime.h>
#include <hip/hip_fp16.h>
#include <cstdint>

#define B_    2
#define T_    2048
#define H_    1024
#define DIN_  2048
#define NS_   16
#define M_    (B_*T_)     // 4096
#define NCHUNK 32
#define LCHUNK 64         // T_/NCHUNK

using bf16x8 = __attribute__((ext_vector_type(8))) short;
using f32x4  = __attribute__((ext_vector_type(4))) float;

__device__ __forceinline__ unsigned short f2bf(float f) {
    union { float f; uint32_t u; } x; x.f = f;
    uint32_t u = x.u;
    uint32_t r = (u + 0x7fffu + ((u >> 16) & 1u)) >> 16;
    return (unsigned short)r;
}
__device__ __forceinline__ float bf2f(unsigned short h) {
    union { uint32_t u; float f; } x; x.u = ((uint32_t)h) << 16;
    return x.f;
}
__device__ __forceinline__ float sigm(float v) { return 1.0f / (1.0f + expf(-v)); }
__device__ __forceinline__ float silu(float v) { return v / (1.0f + expf(-v)); }

__device__ __forceinline__ void gload_lds16(const void* g, void* l) {
    __builtin_amdgcn_global_load_lds(
        (__attribute__((address_space(1))) void*)(void*)g,
        (__attribute__((address_space(3))) void*)l, 16, 0, 0);
}

// ---------------- fused weight prep: transposes to bf16 [N][K] ----------------
// [0,4096) in_proj -> inT; [4096,8192) A_proj -> W2; [8192,10240) out_proj -> outT
__global__ __launch_bounds__(256)
void prep_weights(const float* __restrict__ in_proj, const float* __restrict__ A_proj,
                  const float* __restrict__ out_proj,
                  unsigned short* __restrict__ inT, unsigned short* __restrict__ W2,
                  unsigned short* __restrict__ outT) {
    int bid = blockIdx.x;
    int tid = threadIdx.x;
    const float* src; unsigned short* dst; int K, N, l;
    if (bid < 4096)      { src = in_proj;  dst = inT;  K = 1024; N = 4096; l = bid; }
    else if (bid < 8192) { src = A_proj;   dst = W2;   K = 2048; N = 2048; l = bid - 4096; }
    else                 { src = out_proj; dst = outT; K = 2048; N = 1024; l = bid - 8192; }
    int ntiles = N >> 5;
    int n0 = (l % ntiles) * 32, k0 = (l / ntiles) * 32;
    __shared__ float tile[32][33];
    int tx = tid & 31, ty = tid >> 5;   // ty 0..7
#pragma unroll
    for (int i = 0; i < 32; i += 8)
        tile[ty + i][tx] = src[(size_t)(k0 + ty + i) * N + (n0 + tx)];
    __syncthreads();
    int sx = (tid & 15) * 2;   // k offset, even
    int sy = tid >> 4;         // n 0..15
#pragma unroll
    for (int i = 0; i < 32; i += 16) {
        int n = sy + i;
        float v0 = tile[sx][n], v1 = tile[sx + 1][n];
        size_t o = (size_t)(n0 + n) * K + (k0 + sx);
        *(ushort2*)&dst[o] = make_ushort2(f2bf(v0), f2bf(v1));
    }
}

// ---------------- RMSNorm -> single bf16 ----------------
__global__ __launch_bounds__(256)
void rmsnorm_bf(const float* __restrict__ x, const float* __restrict__ w,
                unsigned short* __restrict__ xh) {
    int row = blockIdx.x;            // 0..4095
    int tid = threadIdx.x;
    const float4* xr = (const float4*)(x + (size_t)row * H_);
    float4 v = xr[tid];
    float ss = v.x * v.x + v.y * v.y + v.z * v.z + v.w * v.w;
#pragma unroll
    for (int o = 32; o > 0; o >>= 1) ss += __shfl_down(ss, o, 64);
    __shared__ float red[4];
    int lane = tid & 63, wv = tid >> 6;
    if (lane == 0) red[wv] = ss;
    __syncthreads();
    float tot = red[0] + red[1] + red[2] + red[3];
    float rstd = rsqrtf(tot / (float)H_ + 1e-6f);
    const float4* wr = (const float4*)w;
    float4 w4 = wr[tid];
    size_t o = (size_t)row * H_ + tid * 4;
    *(ushort4*)&xh[o] = make_ushort4(f2bf(v.x * rstd * w4.x), f2bf(v.y * rstd * w4.y),
                                     f2bf(v.z * rstd * w4.z), f2bf(v.w * rstd * w4.w));
}

// ---------------- bf16 GEMM: C = A @ B^T, TM x TN tile, BK=64, 8 waves ----------------
// r6-proven sync skeleton: 3-buffer ring, stage kt+2 each iter, counted vmcnt(SPW)
// (loads waited were issued 2 iterations earlier). Unit = 16 rows x 32k (1KB), r5-proven
// bank-group XOR swizzle (0 conflicts) + 64B/row global coalescing. XCD swizzle, setprio.
// EPI 0: xz -> silu; col<2048: x_in bf16, else silu_z bf16
// EPI 1: a_mod = sigm(acc + aux[col]) fp16
// EPI 2: out = acc + res[row*1024+col]  (fp32)
template <int EPI, int TM, int TN, int MW, int NW>
__global__ __launch_bounds__(512, 2)
void gemm_bf(const unsigned short* __restrict__ Aa, const unsigned short* __restrict__ Bw,
             int K,
             float* __restrict__ out0,
             unsigned short* __restrict__ oh, unsigned short* __restrict__ oz,
             const float* __restrict__ aux, __half* __restrict__ oha) {
    constexpr int UA    = (TM / 16) * 2;   // A units (16 rows x 32k each)
    constexpr int UB    = (TN / 16) * 2;
    constexpr int UNITS = UA + UB;
    constexpr int SPW   = UNITS / 8;       // stage loads per wave per K-tile
    constexpr int MF    = TM / MW / 16;    // m-frags per wave
    constexpr int NF    = TN / NW / 16;    // n-frags per wave
    __shared__ unsigned short sm[3][UNITS * 512];
    const int tid  = threadIdx.x;
    const int lane = tid & 63;
    const int wid  = tid >> 6;
    const int wm   = wid / NW;
    const int wn   = wid % NW;

    // XCD-chunked bijective block swizzle (grid %8 == 0)
    const int gx   = gridDim.x;
    const int nwg  = gx * gridDim.y;
    const int orig = blockIdx.y * gx + blockIdx.x;
    const int qq   = nwg >> 3;
    const int lid  = (orig & 7) * qq + (orig >> 3);
    const int bm   = (lid / gx) * TM;
    const int bn   = (lid % gx) * TN;

    // staging: lane -> row lane>>2, source granule swizzled within the 64B row
    const unsigned short* b0 = Aa + (size_t)bm * K;
    const unsigned short* b1 = Bw + (size_t)bn * K;
    const int srow  = lane >> 2;
    const int sgran = (lane & 3) ^ ((lane >> 3) & 3);
    const unsigned short* gp[SPW];
    int lofs[SPW];
#pragma unroll
    for (int j = 0; j < SPW; ++j) {
        int u = wid * SPW + j;
        int rel = (u < UA) ? u : (u - UA);
        const unsigned short* base = (u < UA) ? b0 : b1;
        int chunk = rel >> 1, ks = rel & 1;
        gp[j] = base + (size_t)(chunk * 16 + srow) * K + ks * 32 + sgran * 8;
        lofs[j] = u * 512;
    }

    const int nt = K >> 6;
    // prologue: stage tiles 0,1 into buffers 0,1
#pragma unroll
    for (int j = 0; j < SPW; ++j) gload_lds16(gp[j], &sm[0][lofs[j]]);
#pragma unroll
    for (int j = 0; j < SPW; ++j) gload_lds16(gp[j] + 64, &sm[1][lofs[j]]);

    // frag read offset (ushorts) within a unit: r5-proven swizzle
    const int fro = (lane & 15) * 32 + (((lane >> 4) ^ ((lane >> 1) & 3)) * 8);

    f32x4 acc[MF][NF] = {};
    int bsel = 0;
    for (int kt = 0; kt < nt; ++kt) {
        if (kt + 1 < nt) {
            if constexpr (SPW == 6)      asm volatile("s_waitcnt vmcnt(6)" ::: "memory");
            else if constexpr (SPW == 4) asm volatile("s_waitcnt vmcnt(4)" ::: "memory");
            else                         asm volatile("s_waitcnt vmcnt(8)" ::: "memory");
        } else {
            asm volatile("s_waitcnt vmcnt(0)" ::: "memory");
        }
        __builtin_amdgcn_s_barrier();
        __builtin_amdgcn_sched_barrier(0);
        if (kt + 2 < nt) {      // stage tile kt+2 into ring buffer of tile kt-1
            int nb = bsel + 2; if (nb >= 3) nb -= 3;
#pragma unroll
            for (int j = 0; j < SPW; ++j)
                gload_lds16(gp[j] + (size_t)(kt + 2) * 64, &sm[nb][lofs[j]]);
        }
        const unsigned short* sb = sm[bsel];
#pragma unroll
        for (int ks = 0; ks < 2; ++ks) {
            bf16x8 af[MF], bf8[NF];
#pragma unroll
            for (int mf = 0; mf < MF; ++mf)
                af[mf] = *(const bf16x8*)&sb[((wm * MF + mf) * 2 + ks) * 512 + fro];
#pragma unroll
            for (int nf = 0; nf < NF; ++nf)
                bf8[nf] = *(const bf16x8*)&sb[(UA + (wn * NF + nf) * 2 + ks) * 512 + fro];
            __builtin_amdgcn_s_setprio(1);
#pragma unroll
            for (int mf = 0; mf < MF; ++mf)
#pragma unroll
                for (int nf = 0; nf < NF; ++nf)
                    acc[mf][nf] = __builtin_amdgcn_mfma_f32_16x16x32_bf16(af[mf], bf8[nf], acc[mf][nf], 0, 0, 0);
            __builtin_amdgcn_s_setprio(0);
        }
        bsel += 1; if (bsel == 3) bsel = 0;
    }

    // epilogue: C/D layout col=lane&15, row=(lane>>4)*4+reg  [m89-verified]
#pragma unroll
    for (int mf = 0; mf < MF; ++mf)
#pragma unroll
        for (int nf = 0; nf < NF; ++nf) {
            int col  = bn + (wn * NF + nf) * 16 + (lane & 15);
            int row0 = bm + (wm * MF + mf) * 16 + ((lane >> 4) << 2);
#pragma unroll
            for (int r = 0; r < 4; ++r) {
                int row = row0 + r;
                float v = acc[mf][nf][r];
                if (EPI == 0) {
                    float s = silu(v);
                    if (col < DIN_) oh[(size_t)row * DIN_ + col] = f2bf(s);
                    else            oz[(size_t)row * DIN_ + (col - DIN_)] = f2bf(s);
                } else if (EPI == 1) {
                    oha[(size_t)row * DIN_ + col] = __float2half(sigm(v + aux[col]));
                } else {
                    out0[(size_t)row * H_ + col] = v + aux[(size_t)row * H_ + col];
                }
            }
        }
}

// ---------------- B_in / C_in projections (N=16 each) ----------------
__global__ __launch_bounds__(256)
void bc_proj(const unsigned short* __restrict__ xh,
             const float* __restrict__ Bw, const float* __restrict__ Cw,
             float* __restrict__ Bout, float* __restrict__ Cout) {
    int m = blockIdx.x;
    int tid = threadIdx.x;
    float ab[16], ac[16];
#pragma unroll
    for (int i = 0; i < 16; ++i) { ab[i] = 0.f; ac[i] = 0.f; }
    for (int k = tid; k < DIN_; k += 256) {
        float x = bf2f(xh[(size_t)m * DIN_ + k]);
        const float4* br = (const float4*)(Bw + (size_t)k * 16);
        const float4* cr = (const float4*)(Cw + (size_t)k * 16);
#pragma unroll
        for (int j = 0; j < 4; ++j) {
            float4 b4 = br[j], c4 = cr[j];
            ab[j * 4 + 0] = fmaf(x, b4.x, ab[j * 4 + 0]);
            ab[j * 4 + 1] = fmaf(x, b4.y, ab[j * 4 + 1]);
            ab[j * 4 + 2] = fmaf(x, b4.z, ab[j * 4 + 2]);
            ab[j * 4 + 3] = fmaf(x, b4.w, ab[j * 4 + 3]);
            ac[j * 4 + 0] = fmaf(x, c4.x, ac[j * 4 + 0]);
            ac[j * 4 + 1] = fmaf(x, c4.y, ac[j * 4 + 1]);
            ac[j * 4 + 2] = fmaf(x, c4.z, ac[j * 4 + 2]);
            ac[j * 4 + 3] = fmaf(x, c4.w, ac[j * 4 + 3]);
        }
    }
    int lane = tid & 63, w = tid >> 6;
#pragma unroll
    for (int i = 0; i < 16; ++i)
#pragma unroll
        for (int o = 32; o > 0; o >>= 1) {
            ab[i] += __shfl_down(ab[i], o, 64);
            ac[i] += __shfl_down(ac[i], o, 64);
        }
    __shared__ float rb[4][16], rc[4][16];
    if (lane == 0) {
#pragma unroll
        for (int i = 0; i < 16; ++i) { rb[w][i] = ab[i]; rc[w][i] = ac[i]; }
    }
    __syncthreads();
    if (tid < 16) {
        Bout[(size_t)m * 16 + tid] = rb[0][tid] + rb[1][tid] + rb[2][tid] + rb[3][tid];
        Cout[(size_t)m * 16 + tid] = rc[0][tid] + rc[1][tid] + rc[2][tid] + rc[3][tid];
    }
}

// ---------------- chunked parallel scan ----------------
__global__ __launch_bounds__(256)
void scan_phase1(const __half* __restrict__ amod, const unsigned short* __restrict__ xh,
                 const float* __restrict__ Bin, const float* __restrict__ Abase,
                 float* __restrict__ P, float* __restrict__ S) {
    int d = blockIdx.x * 256 + threadIdx.x;   // 0..2047
    int c = blockIdx.y;
    int b = blockIdx.z;
    float ab[16];
#pragma unroll
    for (int n = 0; n < 16; ++n) ab[n] = sigm(Abase[n]);
    float p[16], s[16];
#pragma unroll
    for (int n = 0; n < 16; ++n) { p[n] = 1.0f; s[n] = 0.0f; }
    int t0 = c * LCHUNK;
    for (int tt = 0; tt < LCHUNK; ++tt) {
        size_t mrow = (size_t)(b * T_ + t0 + tt);
        float a = __half2float(amod[mrow * DIN_ + d]);
        float x = bf2f(xh[mrow * DIN_ + d]);
        const float4* bt4 = (const float4*)(Bin + mrow * 16);
        float4 q0 = bt4[0], q1 = bt4[1], q2 = bt4[2], q3 = bt4[3];
        float bt[16];
        bt[0]=q0.x; bt[1]=q0.y; bt[2]=q0.z; bt[3]=q0.w;
        bt[4]=q1.x; bt[5]=q1.y; bt[6]=q1.z; bt[7]=q1.w;
        bt[8]=q2.x; bt[9]=q2.y; bt[10]=q2.z; bt[11]=q2.w;
        bt[12]=q3.x; bt[13]=q3.y; bt[14]=q3.z; bt[15]=q3.w;
#pragma unroll
        for (int n = 0; n < 16; ++n) {
            float dk = a * ab[n];
            p[n] *= dk;
            s[n] = fmaf(dk, s[n], bt[n] * x);
        }
    }
    size_t base = ((size_t)(b * NCHUNK + c) << 15) + (size_t)d * 16;
    float4* P4 = (float4*)(P + base);
    float4* S4 = (float4*)(S + base);
#pragma unroll
    for (int j = 0; j < 4; ++j) {
        P4[j] = make_float4(p[4*j], p[4*j+1], p[4*j+2], p[4*j+3]);
        S4[j] = make_float4(s[4*j], s[4*j+1], s[4*j+2], s[4*j+3]);
    }
}

__global__ __launch_bounds__(256)
void scan_phase2(const float* __restrict__ P, const float* __restrict__ S,
                 float* __restrict__ H0) {
    int idx = blockIdx.x * 256 + threadIdx.x;   // 0..65535
    int b = idx >> 15;
    int dn = idx & 32767;
    float g = 0.f;
    for (int c = 0; c < NCHUNK; ++c) {
        size_t base = ((size_t)(b * NCHUNK + c) << 15) + dn;
        H0[base] = g;
        g = fmaf(P[base], g, S[base]);
    }
}

__global__ __launch_bounds__(256)
void scan_phase3(const __half* __restrict__ amod, const unsigned short* __restrict__ xh,
                 const float* __restrict__ Bin, const float* __restrict__ Cin,
                 const float* __restrict__ Abase, const float* __restrict__ H0,
                 const float* __restrict__ Dp, const unsigned short* __restrict__ szh,
                 unsigned short* __restrict__ yh) {
    int d = blockIdx.x * 256 + threadIdx.x;
    int c = blockIdx.y;
    int b = blockIdx.z;
    float ab[16];
#pragma unroll
    for (int n = 0; n < 16; ++n) ab[n] = sigm(Abase[n]);
    float h[16];
    size_t hbase = ((size_t)(b * NCHUNK + c) << 15) + (size_t)d * 16;
    const float4* H4 = (const float4*)(H0 + hbase);
#pragma unroll
    for (int j = 0; j < 4; ++j) {
        float4 t4 = H4[j];
        h[j*4] = t4.x; h[j*4+1] = t4.y; h[j*4+2] = t4.z; h[j*4+3] = t4.w;
    }
    float Dd = Dp[d];
    int t0 = c * LCHUNK;
    for (int tt = 0; tt < LCHUNK; ++tt) {
        size_t mrow = (size_t)(b * T_ + t0 + tt);
        float a = __half2float(amod[mrow * DIN_ + d]);
        float x = bf2f(xh[mrow * DIN_ + d]);
        const float4* bt4 = (const float4*)(Bin + mrow * 16);
        const float4* ct4 = (const float4*)(Cin + mrow * 16);
        float4 q0 = bt4[0], q1 = bt4[1], q2 = bt4[2], q3 = bt4[3];
        float4 r0 = ct4[0], r1 = ct4[1], r2 = ct4[2], r3 = ct4[3];
        float bt[16], ct[16];
        bt[0]=q0.x; bt[1]=q0.y; bt[2]=q0.z; bt[3]=q0.w;
        bt[4]=q1.x; bt[5]=q1.y; bt[6]=q1.z; bt[7]=q1.w;
        bt[8]=q2.x; bt[9]=q2.y; bt[10]=q2.z; bt[11]=q2.w;
        bt[12]=q3.x; bt[13]=q3.y; bt[14]=q3.z; bt[15]=q3.w;
        ct[0]=r0.x; ct[1]=r0.y; ct[2]=r0.z; ct[3]=r0.w;
        ct[4]=r1.x; ct[5]=r1.y; ct[6]=r1.z; ct[7]=r1.w;
        ct[8]=r2.x; ct[9]=r2.y; ct[10]=r2.z; ct[11]=r2.w;
        ct[12]=r3.x; ct[13]=r3.y; ct[14]=r3.z; ct[15]=r3.w;
        float y = 0.f;
#pragma unroll
        for (int n = 0; n < 16; ++n) {
            float dk = a * ab[n];
            h[n] = fmaf(dk, h[n], bt[n] * x);
            y = fmaf(h[n], ct[n], y);
        }
        float val = (y + Dd * x) * bf2f(szh[mrow * DIN_ + d]);
        yh[mrow * DIN_ + d] = f2bf(val);
    }
}

// ---------------- launch ----------------
extern "C" void kernel_launch(void* const* d_in, const int* in_sizes, int n_in,
                              void* d_out, int out_size, void* d_ws, size_t ws_size,
                              hipStream_t stream) {
    const float* x          = (const float*)d_in[0];
    const float* norm_w     = (const float*)d_in[1];
    const float* in_proj_w  = (const float*)d_in[2];
    const float* A_proj_w   = (const float*)d_in[3];
    const float* A_proj_b   = (const float*)d_in[4];
    const float* A_base     = (const float*)d_in[5];
    const float* B_proj_w   = (const float*)d_in[6];
    const float* C_proj_w   = (const float*)d_in[7];
    const float* Dp         = (const float*)d_in[8];
    const float* out_proj_w = (const float*)d_in[9];
    float* out = (float*)d_out;

    char* ws = (char*)d_ws;
    size_t off = 0;
    auto alloc = [&](size_t bytes) -> char* {
        char* p = ws + off;
        off += (bytes + 255) & ~(size_t)255;
        return p;
    };
    unsigned short* inT  = (unsigned short*)alloc((size_t)4096 * 1024 * 2);
    unsigned short* W2   = (unsigned short*)alloc((size_t)2048 * 2048 * 2);
    unsigned short* outT = (unsigned short*)alloc((size_t)1024 * 2048 * 2);
    unsigned short* xnh  = (unsigned short*)alloc((size_t)M_ * H_ * 2);
    unsigned short* xinh = (unsigned short*)alloc((size_t)M_ * DIN_ * 2);
    unsigned short* szh  = (unsigned short*)alloc((size_t)M_ * DIN_ * 2);
    __half* amod  = (__half*)alloc((size_t)M_ * DIN_ * 2);
    float* Bin    = (float*)alloc((size_t)M_ * 16 * 4);
    float* Cin    = (float*)alloc((size_t)M_ * 16 * 4);
    float* Pw     = (float*)alloc((size_t)B_ * NCHUNK * DIN_ * NS_ * 4);
    float* Sw     = (float*)alloc((size_t)B_ * NCHUNK * DIN_ * NS_ * 4);
    float* H0w    = (float*)alloc((size_t)B_ * NCHUNK * DIN_ * NS_ * 4);
    unsigned short* yh = (unsigned short*)alloc((size_t)M_ * DIN_ * 2);
    (void)ws_size;

    // weight prep (in/A/out transposes; B/C read directly by bc_proj)
    prep_weights<<<10240, 256, 0, stream>>>(in_proj_w, A_proj_w, out_proj_w, inT, W2, outT);

    rmsnorm_bf<<<M_, 256, 0, stream>>>(x, norm_w, xnh);

    // xz = xn @ in_proj  (M=4096, N=4096, K=1024): 256x128, BK=64 -> 512 blocks, 16 iters
    gemm_bf<0, 256, 128, 4, 2><<<dim3(4096 / 128, M_ / 256), 512, 0, stream>>>(
        xnh, inT, 1024, nullptr, xinh, szh, nullptr, nullptr);

    // a_mod = sigmoid(x_in @ A_proj + b)  (N=2048, K=2048): 256x128 -> 256 blocks, 32 iters
    gemm_bf<1, 256, 128, 4, 2><<<dim3(2048 / 128, M_ / 256), 512, 0, stream>>>(
        xinh, W2, 2048, nullptr, nullptr, nullptr, A_proj_b, amod);

    // B_in, C_in (reads x_in bf16 + original fp32 weights)
    bc_proj<<<M_, 256, 0, stream>>>(xinh, B_proj_w, C_proj_w, Bin, Cin);

    // chunked scan
    scan_phase1<<<dim3(DIN_ / 256, NCHUNK, B_), 256, 0, stream>>>(amod, xinh, Bin, A_base, Pw, Sw);
    scan_phase2<<<(B_ * DIN_ * NS_) / 256, 256, 0, stream>>>(Pw, Sw, H0w);
    scan_phase3<<<dim3(DIN_ / 256, NCHUNK, B_), 256, 0, stream>>>(
        amod, xinh, Bin, Cin, A_base, H0w, Dp, szh, yh);

    // out = residual + y @ out_proj  (N=1024, K=2048): 128x128, BK=64 -> 256 blocks, 32 iters
    gemm_bf<2, 128, 128, 2, 4><<<dim3(1024 / 128, M_ / 128), 512, 0, stream>>>(
        yh, outT, 2048, out, nullptr, nullptr, x, nullptr);
}

// Round 9
// 234.807 us; speedup vs baseline: 1.2541x; 1.2541x over previous
//
#include <hip/hip_runtime.h>
#include <hip/hip_fp16.h>
#include <cstdint>

#define B_    2
#define T_    2048
#define H_    1024
#define DIN_  2048
#define NS_   16
#define M_    (B_*T_)     // 4096
#define NCHUNK 64
#define LCHUNK 32         // T_/NCHUNK

using bf16x8 = __attribute__((ext_vector_type(8))) short;
using f32x4  = __attribute__((ext_vector_type(4))) float;

__device__ __forceinline__ unsigned short f2bf(float f) {
    union { float f; uint32_t u; } x; x.f = f;
    uint32_t u = x.u;
    uint32_t r = (u + 0x7fffu + ((u >> 16) & 1u)) >> 16;
    return (unsigned short)r;
}
__device__ __forceinline__ float bf2f(unsigned short h) {
    union { uint32_t u; float f; } x; x.u = ((uint32_t)h) << 16;
    return x.f;
}
__device__ __forceinline__ float sigm(float v) { return 1.0f / (1.0f + expf(-v)); }
__device__ __forceinline__ float silu(float v) { return v / (1.0f + expf(-v)); }

__device__ __forceinline__ void gload_lds16(const void* g, void* l) {
    __builtin_amdgcn_global_load_lds(
        (__attribute__((address_space(1))) void*)(void*)g,
        (__attribute__((address_space(3))) void*)l, 16, 0, 0);
}

// ---------------- fused weight prep: transposes to bf16 [N][K] ----------------
__global__ __launch_bounds__(256)
void prep_weights(const float* __restrict__ in_proj, const float* __restrict__ A_proj,
                  const float* __restrict__ out_proj,
                  unsigned short* __restrict__ inT, unsigned short* __restrict__ W2,
                  unsigned short* __restrict__ outT) {
    int bid = blockIdx.x;
    int tid = threadIdx.x;
    const float* src; unsigned short* dst; int K, N, l;
    if (bid < 4096)      { src = in_proj;  dst = inT;  K = 1024; N = 4096; l = bid; }
    else if (bid < 8192) { src = A_proj;   dst = W2;   K = 2048; N = 2048; l = bid - 4096; }
    else                 { src = out_proj; dst = outT; K = 2048; N = 1024; l = bid - 8192; }
    int ntiles = N >> 5;
    int n0 = (l % ntiles) * 32, k0 = (l / ntiles) * 32;
    __shared__ float tile[32][33];
    int tx = tid & 31, ty = tid >> 5;   // ty 0..7
#pragma unroll
    for (int i = 0; i < 32; i += 8)
        tile[ty + i][tx] = src[(size_t)(k0 + ty + i) * N + (n0 + tx)];
    __syncthreads();
    int sx = (tid & 15) * 2;   // k offset, even
    int sy = tid >> 4;         // n 0..15
#pragma unroll
    for (int i = 0; i < 32; i += 16) {
        int n = sy + i;
        float v0 = tile[sx][n], v1 = tile[sx + 1][n];
        size_t o = (size_t)(n0 + n) * K + (k0 + sx);
        *(ushort2*)&dst[o] = make_ushort2(f2bf(v0), f2bf(v1));
    }
}

// ---------------- RMSNorm -> single bf16 ----------------
__global__ __launch_bounds__(256)
void rmsnorm_bf(const float* __restrict__ x, const float* __restrict__ w,
                unsigned short* __restrict__ xh) {
    int row = blockIdx.x;            // 0..4095
    int tid = threadIdx.x;
    const float4* xr = (const float4*)(x + (size_t)row * H_);
    float4 v = xr[tid];
    float ss = v.x * v.x + v.y * v.y + v.z * v.z + v.w * v.w;
#pragma unroll
    for (int o = 32; o > 0; o >>= 1) ss += __shfl_down(ss, o, 64);
    __shared__ float red[4];
    int lane = tid & 63, wv = tid >> 6;
    if (lane == 0) red[wv] = ss;
    __syncthreads();
    float tot = red[0] + red[1] + red[2] + red[3];
    float rstd = rsqrtf(tot / (float)H_ + 1e-6f);
    const float4* wr = (const float4*)w;
    float4 w4 = wr[tid];
    size_t o = (size_t)row * H_ + tid * 4;
    *(ushort4*)&xh[o] = make_ushort4(f2bf(v.x * rstd * w4.x), f2bf(v.y * rstd * w4.y),
                                     f2bf(v.z * rstd * w4.z), f2bf(v.w * rstd * w4.w));
}

// ---------------- bf16 GEMM: C = A @ B^T, TM x TN tile, BK=64, 8 waves ----------------
// r6-proven sync skeleton: 3-buffer ring, stage kt+2 each iter, counted vmcnt(SPW).
// Unit = 16 rows x 32k (1KB), r5-proven bank-group XOR swizzle + 64B/row coalescing.
// EPI 0: xz -> silu; col<2048: x_in bf16, else silu_z bf16
// EPI 1: a_mod = sigm(acc + aux[col]) fp16
// EPI 2: out = acc + res[row*1024+col]  (fp32)
template <int EPI, int TM, int TN, int MW, int NW>
__global__ __launch_bounds__(512, 2)
void gemm_bf(const unsigned short* __restrict__ Aa, const unsigned short* __restrict__ Bw,
             int K,
             float* __restrict__ out0,
             unsigned short* __restrict__ oh, unsigned short* __restrict__ oz,
             const float* __restrict__ aux, __half* __restrict__ oha) {
    constexpr int UA    = (TM / 16) * 2;   // A units (16 rows x 32k each)
    constexpr int UB    = (TN / 16) * 2;
    constexpr int UNITS = UA + UB;
    constexpr int SPW   = UNITS / 8;       // stage loads per wave per K-tile
    constexpr int MF    = TM / MW / 16;    // m-frags per wave
    constexpr int NF    = TN / NW / 16;    // n-frags per wave
    __shared__ unsigned short sm[3][UNITS * 512];
    const int tid  = threadIdx.x;
    const int lane = tid & 63;
    const int wid  = tid >> 6;
    const int wm   = wid / NW;
    const int wn   = wid % NW;

    // XCD-chunked bijective block swizzle (grid %8 == 0)
    const int gx   = gridDim.x;
    const int nwg  = gx * gridDim.y;
    const int orig = blockIdx.y * gx + blockIdx.x;
    const int qq   = nwg >> 3;
    const int lid  = (orig & 7) * qq + (orig >> 3);
    const int bm   = (lid / gx) * TM;
    const int bn   = (lid % gx) * TN;

    // staging: lane -> row lane>>2, source granule swizzled within the 64B row
    const unsigned short* b0 = Aa + (size_t)bm * K;
    const unsigned short* b1 = Bw + (size_t)bn * K;
    const int srow  = lane >> 2;
    const int sgran = (lane & 3) ^ ((lane >> 3) & 3);
    const unsigned short* gp[SPW];
    int lofs[SPW];
#pragma unroll
    for (int j = 0; j < SPW; ++j) {
        int u = wid * SPW + j;
        int rel = (u < UA) ? u : (u - UA);
        const unsigned short* base = (u < UA) ? b0 : b1;
        int chunk = rel >> 1, ks = rel & 1;
        gp[j] = base + (size_t)(chunk * 16 + srow) * K + ks * 32 + sgran * 8;
        lofs[j] = u * 512;
    }

    const int nt = K >> 6;
    // prologue: stage tiles 0,1 into buffers 0,1
#pragma unroll
    for (int j = 0; j < SPW; ++j) gload_lds16(gp[j], &sm[0][lofs[j]]);
#pragma unroll
    for (int j = 0; j < SPW; ++j) gload_lds16(gp[j] + 64, &sm[1][lofs[j]]);

    // frag read offset (ushorts) within a unit: r5-proven swizzle
    const int fro = (lane & 15) * 32 + (((lane >> 4) ^ ((lane >> 1) & 3)) * 8);

    f32x4 acc[MF][NF] = {};
    int bsel = 0;
    for (int kt = 0; kt < nt; ++kt) {
        if (kt + 1 < nt) {
            if constexpr (SPW == 6)      asm volatile("s_waitcnt vmcnt(6)" ::: "memory");
            else if constexpr (SPW == 4) asm volatile("s_waitcnt vmcnt(4)" ::: "memory");
            else                         asm volatile("s_waitcnt vmcnt(8)" ::: "memory");
        } else {
            asm volatile("s_waitcnt vmcnt(0)" ::: "memory");
        }
        __builtin_amdgcn_s_barrier();
        __builtin_amdgcn_sched_barrier(0);
        if (kt + 2 < nt) {      // stage tile kt+2 into ring buffer of tile kt-1
            int nb = bsel + 2; if (nb >= 3) nb -= 3;
#pragma unroll
            for (int j = 0; j < SPW; ++j)
                gload_lds16(gp[j] + (size_t)(kt + 2) * 64, &sm[nb][lofs[j]]);
        }
        const unsigned short* sb = sm[bsel];
#pragma unroll
        for (int ks = 0; ks < 2; ++ks) {
            bf16x8 af[MF], bf8[NF];
#pragma unroll
            for (int mf = 0; mf < MF; ++mf)
                af[mf] = *(const bf16x8*)&sb[((wm * MF + mf) * 2 + ks) * 512 + fro];
#pragma unroll
            for (int nf = 0; nf < NF; ++nf)
                bf8[nf] = *(const bf16x8*)&sb[(UA + (wn * NF + nf) * 2 + ks) * 512 + fro];
            __builtin_amdgcn_s_setprio(1);
#pragma unroll
            for (int mf = 0; mf < MF; ++mf)
#pragma unroll
                for (int nf = 0; nf < NF; ++nf)
                    acc[mf][nf] = __builtin_amdgcn_mfma_f32_16x16x32_bf16(af[mf], bf8[nf], acc[mf][nf], 0, 0, 0);
            __builtin_amdgcn_s_setprio(0);
        }
        bsel += 1; if (bsel == 3) bsel = 0;
    }

    // epilogue: C/D layout col=lane&15, row=(lane>>4)*4+reg  [m89-verified]
#pragma unroll
    for (int mf = 0; mf < MF; ++mf)
#pragma unroll
        for (int nf = 0; nf < NF; ++nf) {
            int col  = bn + (wn * NF + nf) * 16 + (lane & 15);
            int row0 = bm + (wm * MF + mf) * 16 + ((lane >> 4) << 2);
#pragma unroll
            for (int r = 0; r < 4; ++r) {
                int row = row0 + r;
                float v = acc[mf][nf][r];
                if (EPI == 0) {
                    float s = silu(v);
                    if (col < DIN_) oh[(size_t)row * DIN_ + col] = f2bf(s);
                    else            oz[(size_t)row * DIN_ + (col - DIN_)] = f2bf(s);
                } else if (EPI == 1) {
                    oha[(size_t)row * DIN_ + col] = __float2half(sigm(v + aux[col]));
                } else {
                    out0[(size_t)row * H_ + col] = v + aux[(size_t)row * H_ + col];
                }
            }
        }
}

// ---------------- B_in / C_in projections, LDS-staged weights ----------------
// 256 blocks x 16 rows; 16 k-lanes per row; weights staged per 512-k tile.
// LDS pad 17: bank (17*j+c) mod 32 distinct over j=0..15 -> conflict-free.
#define KT_ 512
__global__ __launch_bounds__(256)
void bc_proj(const unsigned short* __restrict__ xh,
             const float* __restrict__ Bw, const float* __restrict__ Cw,
             float* __restrict__ Bout, float* __restrict__ Cout) {
    __shared__ float wB[KT_][17];
    __shared__ float wC[KT_][17];
    const int m0  = blockIdx.x * 16;
    const int tid = threadIdx.x;
    const int r   = tid >> 4;      // 0..15 row within block
    const int j   = tid & 15;      // k-lane
    float ab[16], ac[16];
#pragma unroll
    for (int i = 0; i < 16; ++i) { ab[i] = 0.f; ac[i] = 0.f; }

    for (int kt = 0; kt < DIN_; kt += KT_) {
        if (kt) __syncthreads();   // protect LDS from previous compute
        const float4* bs = (const float4*)(Bw + (size_t)kt * 16);
        const float4* cs = (const float4*)(Cw + (size_t)kt * 16);
#pragma unroll
        for (int i = 0; i < 8; ++i) {
            int idx = i * 256 + tid;          // 0..2047 float4s
            int kk = idx >> 2, c4 = (idx & 3) * 4;
            float4 vb = bs[idx], vc = cs[idx];
            wB[kk][c4 + 0] = vb.x; wB[kk][c4 + 1] = vb.y; wB[kk][c4 + 2] = vb.z; wB[kk][c4 + 3] = vb.w;
            wC[kk][c4 + 0] = vc.x; wC[kk][c4 + 1] = vc.y; wC[kk][c4 + 2] = vc.z; wC[kk][c4 + 3] = vc.w;
        }
        __syncthreads();
        const unsigned short* xr = xh + (size_t)(m0 + r) * DIN_ + kt;
#pragma unroll 4
        for (int kk = 0; kk < 32; ++kk) {
            int kl = kk * 16 + j;
            float x = bf2f(xr[kl]);
#pragma unroll
            for (int c = 0; c < 16; ++c) {
                ab[c] = fmaf(x, wB[kl][c], ab[c]);
                ac[c] = fmaf(x, wC[kl][c], ac[c]);
            }
        }
    }
    // reduce over the 16 k-lanes (xor masks < 16 keep r fixed)
#pragma unroll
    for (int i = 0; i < 16; ++i) {
#pragma unroll
        for (int m = 8; m > 0; m >>= 1) {
            ab[i] += __shfl_xor(ab[i], m, 64);
            ac[i] += __shfl_xor(ac[i], m, 64);
        }
    }
    if (j == 0) {
#pragma unroll
        for (int i = 0; i < 16; ++i) {
            Bout[(size_t)(m0 + r) * 16 + i] = ab[i];
            Cout[(size_t)(m0 + r) * 16 + i] = ac[i];
        }
    }
}

// ---------------- chunked parallel scan ----------------
__global__ __launch_bounds__(256)
void scan_phase1(const __half* __restrict__ amod, const unsigned short* __restrict__ xh,
                 const float* __restrict__ Bin, const float* __restrict__ Abase,
                 float* __restrict__ P, float* __restrict__ S) {
    int d = blockIdx.x * 256 + threadIdx.x;   // 0..2047
    int c = blockIdx.y;
    int b = blockIdx.z;
    float ab[16];
#pragma unroll
    for (int n = 0; n < 16; ++n) ab[n] = sigm(Abase[n]);
    float p[16], s[16];
#pragma unroll
    for (int n = 0; n < 16; ++n) { p[n] = 1.0f; s[n] = 0.0f; }
    int t0 = c * LCHUNK;
    for (int tt = 0; tt < LCHUNK; ++tt) {
        size_t mrow = (size_t)(b * T_ + t0 + tt);
        float a = __half2float(amod[mrow * DIN_ + d]);
        float x = bf2f(xh[mrow * DIN_ + d]);
        const float4* bt4 = (const float4*)(Bin + mrow * 16);
        float4 q0 = bt4[0], q1 = bt4[1], q2 = bt4[2], q3 = bt4[3];
        float bt[16];
        bt[0]=q0.x; bt[1]=q0.y; bt[2]=q0.z; bt[3]=q0.w;
        bt[4]=q1.x; bt[5]=q1.y; bt[6]=q1.z; bt[7]=q1.w;
        bt[8]=q2.x; bt[9]=q2.y; bt[10]=q2.z; bt[11]=q2.w;
        bt[12]=q3.x; bt[13]=q3.y; bt[14]=q3.z; bt[15]=q3.w;
#pragma unroll
        for (int n = 0; n < 16; ++n) {
            float dk = a * ab[n];
            p[n] *= dk;
            s[n] = fmaf(dk, s[n], bt[n] * x);
        }
    }
    size_t base = ((size_t)(b * NCHUNK + c) << 15) + (size_t)d * 16;
    float4* P4 = (float4*)(P + base);
    float4* S4 = (float4*)(S + base);
#pragma unroll
    for (int j = 0; j < 4; ++j) {
        P4[j] = make_float4(p[4*j], p[4*j+1], p[4*j+2], p[4*j+3]);
        S4[j] = make_float4(s[4*j], s[4*j+1], s[4*j+2], s[4*j+3]);
    }
}

__global__ __launch_bounds__(256)
void scan_phase2(const float* __restrict__ P, const float* __restrict__ S,
                 float* __restrict__ H0) {
    int idx = blockIdx.x * 256 + threadIdx.x;   // 0..65535
    int b = idx >> 15;
    int dn = idx & 32767;
    float g = 0.f;
    for (int c = 0; c < NCHUNK; ++c) {
        size_t base = ((size_t)(b * NCHUNK + c) << 15) + dn;
        H0[base] = g;
        g = fmaf(P[base], g, S[base]);
    }
}

__global__ __launch_bounds__(256)
void scan_phase3(const __half* __restrict__ amod, const unsigned short* __restrict__ xh,
                 const float* __restrict__ Bin, const float* __restrict__ Cin,
                 const float* __restrict__ Abase, const float* __restrict__ H0,
                 const float* __restrict__ Dp, const unsigned short* __restrict__ szh,
                 unsigned short* __restrict__ yh) {
    int d = blockIdx.x * 256 + threadIdx.x;
    int c = blockIdx.y;
    int b = blockIdx.z;
    float ab[16];
#pragma unroll
    for (int n = 0; n < 16; ++n) ab[n] = sigm(Abase[n]);
    float h[16];
    size_t hbase = ((size_t)(b * NCHUNK + c) << 15) + (size_t)d * 16;
    const float4* H4 = (const float4*)(H0 + hbase);
#pragma unroll
    for (int j = 0; j < 4; ++j) {
        float4 t4 = H4[j];
        h[j*4] = t4.x; h[j*4+1] = t4.y; h[j*4+2] = t4.z; h[j*4+3] = t4.w;
    }
    float Dd = Dp[d];
    int t0 = c * LCHUNK;
    for (int tt = 0; tt < LCHUNK; ++tt) {
        size_t mrow = (size_t)(b * T_ + t0 + tt);
        float a = __half2float(amod[mrow * DIN_ + d]);
        float x = bf2f(xh[mrow * DIN_ + d]);
        const float4* bt4 = (const float4*)(Bin + mrow * 16);
        const float4* ct4 = (const float4*)(Cin + mrow * 16);
        float4 q0 = bt4[0], q1 = bt4[1], q2 = bt4[2], q3 = bt4[3];
        float4 r0 = ct4[0], r1 = ct4[1], r2 = ct4[2], r3 = ct4[3];
        float bt[16], ct[16];
        bt[0]=q0.x; bt[1]=q0.y; bt[2]=q0.z; bt[3]=q0.w;
        bt[4]=q1.x; bt[5]=q1.y; bt[6]=q1.z; bt[7]=q1.w;
        bt[8]=q2.x; bt[9]=q2.y; bt[10]=q2.z; bt[11]=q2.w;
        bt[12]=q3.x; bt[13]=q3.y; bt[14]=q3.z; bt[15]=q3.w;
        ct[0]=r0.x; ct[1]=r0.y; ct[2]=r0.z; ct[3]=r0.w;
        ct[4]=r1.x; ct[5]=r1.y; ct[6]=r1.z; ct[7]=r1.w;
        ct[8]=r2.x; ct[9]=r2.y; ct[10]=r2.z; ct[11]=r2.w;
        ct[12]=r3.x; ct[13]=r3.y; ct[14]=r3.z; ct[15]=r3.w;
        float y = 0.f;
#pragma unroll
        for (int n = 0; n < 16; ++n) {
            float dk = a * ab[n];
            h[n] = fmaf(dk, h[n], bt[n] * x);
            y = fmaf(h[n], ct[n], y);
        }
        float val = (y + Dd * x) * bf2f(szh[mrow * DIN_ + d]);
        yh[mrow * DIN_ + d] = f2bf(val);
    }
}

// ---------------- launch ----------------
extern "C" void kernel_launch(void* const* d_in, const int* in_sizes, int n_in,
                              void* d_out, int out_size, void* d_ws, size_t ws_size,
                              hipStream_t stream) {
    const float* x          = (const float*)d_in[0];
    const float* norm_w     = (const float*)d_in[1];
    const float* in_proj_w  = (const float*)d_in[2];
    const float* A_proj_w   = (const float*)d_in[3];
    const float* A_proj_b   = (const float*)d_in[4];
    const float* A_base     = (const float*)d_in[5];
    const float* B_proj_w   = (const float*)d_in[6];
    const float* C_proj_w   = (const float*)d_in[7];
    const float* Dp         = (const float*)d_in[8];
    const float* out_proj_w = (const float*)d_in[9];
    float* out = (float*)d_out;

    char* ws = (char*)d_ws;
    size_t off = 0;
    auto alloc = [&](size_t bytes) -> char* {
        char* p = ws + off;
        off += (bytes + 255) & ~(size_t)255;
        return p;
    };
    unsigned short* inT  = (unsigned short*)alloc((size_t)4096 * 1024 * 2);
    unsigned short* W2   = (unsigned short*)alloc((size_t)2048 * 2048 * 2);
    unsigned short* outT = (unsigned short*)alloc((size_t)1024 * 2048 * 2);
    unsigned short* xnh  = (unsigned short*)alloc((size_t)M_ * H_ * 2);
    unsigned short* xinh = (unsigned short*)alloc((size_t)M_ * DIN_ * 2);
    unsigned short* szh  = (unsigned short*)alloc((size_t)M_ * DIN_ * 2);
    __half* amod  = (__half*)alloc((size_t)M_ * DIN_ * 2);
    float* Bin    = (float*)alloc((size_t)M_ * 16 * 4);
    float* Cin    = (float*)alloc((size_t)M_ * 16 * 4);
    float* Pw     = (float*)alloc((size_t)B_ * NCHUNK * DIN_ * NS_ * 4);
    float* Sw     = (float*)alloc((size_t)B_ * NCHUNK * DIN_ * NS_ * 4);
    float* H0w    = (float*)alloc((size_t)B_ * NCHUNK * DIN_ * NS_ * 4);
    unsigned short* yh = (unsigned short*)alloc((size_t)M_ * DIN_ * 2);
    (void)ws_size;

    // weight prep (in/A/out transposes; B/C read directly by bc_proj)
    prep_weights<<<10240, 256, 0, stream>>>(in_proj_w, A_proj_w, out_proj_w, inT, W2, outT);

    rmsnorm_bf<<<M_, 256, 0, stream>>>(x, norm_w, xnh);

    // xz = xn @ in_proj  (M=4096, N=4096, K=1024): 256x128, BK=64 -> 512 blocks, 16 iters
    gemm_bf<0, 256, 128, 4, 2><<<dim3(4096 / 128, M_ / 256), 512, 0, stream>>>(
        xnh, inT, 1024, nullptr, xinh, szh, nullptr, nullptr);

    // a_mod = sigmoid(x_in @ A_proj + b)  (N=2048, K=2048): 256x128 -> 256 blocks, 32 iters
    gemm_bf<1, 256, 128, 4, 2><<<dim3(2048 / 128, M_ / 256), 512, 0, stream>>>(
        xinh, W2, 2048, nullptr, nullptr, nullptr, A_proj_b, amod);

    // B_in, C_in (LDS-staged weights, 16 rows/block)
    bc_proj<<<M_ / 16, 256, 0, stream>>>(xinh, B_proj_w, C_proj_w, Bin, Cin);

    // chunked scan (NCHUNK=64)
    scan_phase1<<<dim3(DIN_ / 256, NCHUNK, B_), 256, 0, stream>>>(amod, xinh, Bin, A_base, Pw, Sw);
    scan_phase2<<<(B_ * DIN_ * NS_) / 256, 256, 0, stream>>>(Pw, Sw, H0w);
    scan_phase3<<<dim3(DIN_ / 256, NCHUNK, B_), 256, 0, stream>>>(
        amod, xinh, Bin, Cin, A_base, H0w, Dp, szh, yh);

    // out = residual + y @ out_proj  (N=1024, K=2048): 128x128, BK=64 -> 256 blocks, 32 iters
    gemm_bf<2, 128, 128, 2, 4><<<dim3(1024 / 128, M_ / 128), 512, 0, stream>>>(
        yh, outT, 2048, out, nullptr, nullptr, x, nullptr);
}

// Round 10
// 232.805 us; speedup vs baseline: 1.2649x; 1.0086x over previous
//
#include <hip/hip_runtime.h>
#include <hip/hip_fp16.h>
#include <cstdint>

#define B_    2
#define T_    2048
#define H_    1024
#define DIN_  2048
#define NS_   16
#define M_    (B_*T_)     // 4096
#define NCHUNK 64
#define LCHUNK 32         // T_/NCHUNK

using bf16x8 = __attribute__((ext_vector_type(8))) short;
using f32x4  = __attribute__((ext_vector_type(4))) float;

__device__ __forceinline__ unsigned short f2bf(float f) {
    union { float f; uint32_t u; } x; x.f = f;
    uint32_t u = x.u;
    uint32_t r = (u + 0x7fffu + ((u >> 16) & 1u)) >> 16;
    return (unsigned short)r;
}
__device__ __forceinline__ float bf2f(unsigned short h) {
    union { uint32_t u; float f; } x; x.u = ((uint32_t)h) << 16;
    return x.f;
}
__device__ __forceinline__ float sigm(float v) { return 1.0f / (1.0f + expf(-v)); }
__device__ __forceinline__ float silu(float v) { return v / (1.0f + expf(-v)); }

__device__ __forceinline__ void gload_lds16(const void* g, void* l) {
    __builtin_amdgcn_global_load_lds(
        (__attribute__((address_space(1))) void*)(void*)g,
        (__attribute__((address_space(3))) void*)l, 16, 0, 0);
}

// ---------------- fused weight prep: transposes to bf16 [N][K] ----------------
__global__ __launch_bounds__(256)
void prep_weights(const float* __restrict__ in_proj, const float* __restrict__ A_proj,
                  const float* __restrict__ out_proj,
                  unsigned short* __restrict__ inT, unsigned short* __restrict__ W2,
                  unsigned short* __restrict__ outT) {
    int bid = blockIdx.x;
    int tid = threadIdx.x;
    const float* src; unsigned short* dst; int K, N, l;
    if (bid < 4096)      { src = in_proj;  dst = inT;  K = 1024; N = 4096; l = bid; }
    else if (bid < 8192) { src = A_proj;   dst = W2;   K = 2048; N = 2048; l = bid - 4096; }
    else                 { src = out_proj; dst = outT; K = 2048; N = 1024; l = bid - 8192; }
    int ntiles = N >> 5;
    int n0 = (l % ntiles) * 32, k0 = (l / ntiles) * 32;
    __shared__ float tile[32][33];
    int tx = tid & 31, ty = tid >> 5;   // ty 0..7
#pragma unroll
    for (int i = 0; i < 32; i += 8)
        tile[ty + i][tx] = src[(size_t)(k0 + ty + i) * N + (n0 + tx)];
    __syncthreads();
    int sx = (tid & 15) * 2;   // k offset, even
    int sy = tid >> 4;         // n 0..15
#pragma unroll
    for (int i = 0; i < 32; i += 16) {
        int n = sy + i;
        float v0 = tile[sx][n], v1 = tile[sx + 1][n];
        size_t o = (size_t)(n0 + n) * K + (k0 + sx);
        *(ushort2*)&dst[o] = make_ushort2(f2bf(v0), f2bf(v1));
    }
}

// ---------------- RMSNorm -> single bf16 ----------------
__global__ __launch_bounds__(256)
void rmsnorm_bf(const float* __restrict__ x, const float* __restrict__ w,
                unsigned short* __restrict__ xh) {
    int row = blockIdx.x;            // 0..4095
    int tid = threadIdx.x;
    const float4* xr = (const float4*)(x + (size_t)row * H_);
    float4 v = xr[tid];
    float ss = v.x * v.x + v.y * v.y + v.z * v.z + v.w * v.w;
#pragma unroll
    for (int o = 32; o > 0; o >>= 1) ss += __shfl_down(ss, o, 64);
    __shared__ float red[4];
    int lane = tid & 63, wv = tid >> 6;
    if (lane == 0) red[wv] = ss;
    __syncthreads();
    float tot = red[0] + red[1] + red[2] + red[3];
    float rstd = rsqrtf(tot / (float)H_ + 1e-6f);
    const float4* wr = (const float4*)w;
    float4 w4 = wr[tid];
    size_t o = (size_t)row * H_ + tid * 4;
    *(ushort4*)&xh[o] = make_ushort4(f2bf(v.x * rstd * w4.x), f2bf(v.y * rstd * w4.y),
                                     f2bf(v.z * rstd * w4.z), f2bf(v.w * rstd * w4.w));
}

// ---------------- bf16 GEMM: C = A @ B^T, TM x TN tile, BK=64, 8 waves ----------------
// r6/r9-proven sync topology: 3-buffer ring, stage kt+2, counted vmcnt(SPW) at tile top.
// NEW (r10): 2 interleave-phases per K-tile (ks-split): each phase does
// {ds_read ks-frags || issue SPW/2 stage gloads || setprio MFMA x (MF*NF)} + mid barrier
// -> wave role diversity (T3-lite), activates T5. Per-wave tile 128x32 (MF=8,NF=2).
// Unit = 16 rows x 32k (1KB), r5-proven XOR swizzle (0 conflicts) + 64B/row coalescing.
// EPI 0: xz -> silu; col<2048: x_in bf16, else silu_z bf16
// EPI 1: a_mod = sigm(acc + aux[col]) fp16
// EPI 2: out = acc + res[row*1024+col]  (fp32)
template <int EPI, int TM, int TN, int MW, int NW>
__global__ __launch_bounds__(512, 2)
void gemm_bf(const unsigned short* __restrict__ Aa, const unsigned short* __restrict__ Bw,
             int K,
             float* __restrict__ out0,
             unsigned short* __restrict__ oh, unsigned short* __restrict__ oz,
             const float* __restrict__ aux, __half* __restrict__ oha) {
    constexpr int UA    = (TM / 16) * 2;   // A units (16 rows x 32k each)
    constexpr int UB    = (TN / 16) * 2;
    constexpr int UNITS = UA + UB;
    constexpr int SPW   = UNITS / 8;       // stage loads per wave per K-tile
    constexpr int MF    = TM / MW / 16;    // m-frags per wave
    constexpr int NF    = TN / NW / 16;    // n-frags per wave
    __shared__ unsigned short sm[3][UNITS * 512];
    const int tid  = threadIdx.x;
    const int lane = tid & 63;
    const int wid  = tid >> 6;
    const int wm   = wid / NW;
    const int wn   = wid % NW;

    // XCD-chunked bijective block swizzle (grid %8 == 0)
    const int gx   = gridDim.x;
    const int nwg  = gx * gridDim.y;
    const int orig = blockIdx.y * gx + blockIdx.x;
    const int qq   = nwg >> 3;
    const int lid  = (orig & 7) * qq + (orig >> 3);
    const int bm   = (lid / gx) * TM;
    const int bn   = (lid % gx) * TN;

    // staging: lane -> row lane>>2, source granule swizzled within the 64B row
    const unsigned short* b0 = Aa + (size_t)bm * K;
    const unsigned short* b1 = Bw + (size_t)bn * K;
    const int srow  = lane >> 2;
    const int sgran = (lane & 3) ^ ((lane >> 3) & 3);
    const unsigned short* gp[SPW];
    int lofs[SPW];
#pragma unroll
    for (int j = 0; j < SPW; ++j) {
        int u = wid * SPW + j;
        int rel = (u < UA) ? u : (u - UA);
        const unsigned short* base = (u < UA) ? b0 : b1;
        int chunk = rel >> 1, ks = rel & 1;
        gp[j] = base + (size_t)(chunk * 16 + srow) * K + ks * 32 + sgran * 8;
        lofs[j] = u * 512;
    }

    const int nt = K >> 6;
    // prologue: stage tiles 0,1 into buffers 0,1
#pragma unroll
    for (int j = 0; j < SPW; ++j) gload_lds16(gp[j], &sm[0][lofs[j]]);
#pragma unroll
    for (int j = 0; j < SPW; ++j) gload_lds16(gp[j] + 64, &sm[1][lofs[j]]);

    // frag read offset (ushorts) within a unit: r5-proven swizzle
    const int fro = (lane & 15) * 32 + (((lane >> 4) ^ ((lane >> 1) & 3)) * 8);

    f32x4 acc[MF][NF] = {};
    int bsel = 0;
    for (int kt = 0; kt < nt; ++kt) {
        if (kt + 1 < nt) {
            if constexpr (SPW == 6)      asm volatile("s_waitcnt vmcnt(6)" ::: "memory");
            else if constexpr (SPW == 4) asm volatile("s_waitcnt vmcnt(4)" ::: "memory");
            else                         asm volatile("s_waitcnt vmcnt(8)" ::: "memory");
        } else {
            asm volatile("s_waitcnt vmcnt(0)" ::: "memory");
        }
        __builtin_amdgcn_s_barrier();
        __builtin_amdgcn_sched_barrier(0);
        int nb = bsel + 2; if (nb >= 3) nb -= 3;
        const unsigned short* sb = sm[bsel];
        const bool pf = (kt + 2 < nt);
#pragma unroll
        for (int ks = 0; ks < 2; ++ks) {
            bf16x8 af[MF], bf8[NF];
#pragma unroll
            for (int mf = 0; mf < MF; ++mf)
                af[mf] = *(const bf16x8*)&sb[((wm * MF + mf) * 2 + ks) * 512 + fro];
#pragma unroll
            for (int nf = 0; nf < NF; ++nf)
                bf8[nf] = *(const bf16x8*)&sb[(UA + (wn * NF + nf) * 2 + ks) * 512 + fro];
            if (pf) {
#pragma unroll
                for (int j = 0; j < SPW / 2; ++j) {
                    int jj = ks * (SPW / 2) + j;
                    gload_lds16(gp[jj] + (size_t)(kt + 2) * 64, &sm[nb][lofs[jj]]);
                }
            }
            __builtin_amdgcn_s_setprio(1);
#pragma unroll
            for (int mf = 0; mf < MF; ++mf)
#pragma unroll
                for (int nf = 0; nf < NF; ++nf)
                    acc[mf][nf] = __builtin_amdgcn_mfma_f32_16x16x32_bf16(af[mf], bf8[nf], acc[mf][nf], 0, 0, 0);
            __builtin_amdgcn_s_setprio(0);
            if (ks == 0) {          // mid-tile phase barrier (role stagger)
                __builtin_amdgcn_s_barrier();
                __builtin_amdgcn_sched_barrier(0);
            }
        }
        bsel += 1; if (bsel == 3) bsel = 0;
    }

    // epilogue: C/D layout col=lane&15, row=(lane>>4)*4+reg  [m89-verified]
#pragma unroll
    for (int mf = 0; mf < MF; ++mf)
#pragma unroll
        for (int nf = 0; nf < NF; ++nf) {
            int col  = bn + (wn * NF + nf) * 16 + (lane & 15);
            int row0 = bm + (wm * MF + mf) * 16 + ((lane >> 4) << 2);
#pragma unroll
            for (int r = 0; r < 4; ++r) {
                int row = row0 + r;
                float v = acc[mf][nf][r];
                if (EPI == 0) {
                    float s = silu(v);
                    if (col < DIN_) oh[(size_t)row * DIN_ + col] = f2bf(s);
                    else            oz[(size_t)row * DIN_ + (col - DIN_)] = f2bf(s);
                } else if (EPI == 1) {
                    oha[(size_t)row * DIN_ + col] = __float2half(sigm(v + aux[col]));
                } else {
                    out0[(size_t)row * H_ + col] = v + aux[(size_t)row * H_ + col];
                }
            }
        }
}

// ---------------- B_in / C_in projections, LDS-staged weights ----------------
#define KT_ 512
__global__ __launch_bounds__(256)
void bc_proj(const unsigned short* __restrict__ xh,
             const float* __restrict__ Bw, const float* __restrict__ Cw,
             float* __restrict__ Bout, float* __restrict__ Cout) {
    __shared__ float wB[KT_][17];
    __shared__ float wC[KT_][17];
    const int m0  = blockIdx.x * 16;
    const int tid = threadIdx.x;
    const int r   = tid >> 4;      // 0..15 row within block
    const int j   = tid & 15;      // k-lane
    float ab[16], ac[16];
#pragma unroll
    for (int i = 0; i < 16; ++i) { ab[i] = 0.f; ac[i] = 0.f; }

    for (int kt = 0; kt < DIN_; kt += KT_) {
        if (kt) __syncthreads();
        const float4* bs = (const float4*)(Bw + (size_t)kt * 16);
        const float4* cs = (const float4*)(Cw + (size_t)kt * 16);
#pragma unroll
        for (int i = 0; i < 8; ++i) {
            int idx = i * 256 + tid;
            int kk = idx >> 2, c4 = (idx & 3) * 4;
            float4 vb = bs[idx], vc = cs[idx];
            wB[kk][c4 + 0] = vb.x; wB[kk][c4 + 1] = vb.y; wB[kk][c4 + 2] = vb.z; wB[kk][c4 + 3] = vb.w;
            wC[kk][c4 + 0] = vc.x; wC[kk][c4 + 1] = vc.y; wC[kk][c4 + 2] = vc.z; wC[kk][c4 + 3] = vc.w;
        }
        __syncthreads();
        const unsigned short* xr = xh + (size_t)(m0 + r) * DIN_ + kt;
#pragma unroll 4
        for (int kk = 0; kk < 32; ++kk) {
            int kl = kk * 16 + j;
            float x = bf2f(xr[kl]);
#pragma unroll
            for (int c = 0; c < 16; ++c) {
                ab[c] = fmaf(x, wB[kl][c], ab[c]);
                ac[c] = fmaf(x, wC[kl][c], ac[c]);
            }
        }
    }
#pragma unroll
    for (int i = 0; i < 16; ++i) {
#pragma unroll
        for (int m = 8; m > 0; m >>= 1) {
            ab[i] += __shfl_xor(ab[i], m, 64);
            ac[i] += __shfl_xor(ac[i], m, 64);
        }
    }
    if (j == 0) {
#pragma unroll
        for (int i = 0; i < 16; ++i) {
            Bout[(size_t)(m0 + r) * 16 + i] = ab[i];
            Cout[(size_t)(m0 + r) * 16 + i] = ac[i];
        }
    }
}

// ---------------- chunked parallel scan ----------------
__global__ __launch_bounds__(256)
void scan_phase1(const __half* __restrict__ amod, const unsigned short* __restrict__ xh,
                 const float* __restrict__ Bin, const float* __restrict__ Abase,
                 float* __restrict__ P, float* __restrict__ S) {
    int d = blockIdx.x * 256 + threadIdx.x;   // 0..2047
    int c = blockIdx.y;
    int b = blockIdx.z;
    float ab[16];
#pragma unroll
    for (int n = 0; n < 16; ++n) ab[n] = sigm(Abase[n]);
    float p[16], s[16];
#pragma unroll
    for (int n = 0; n < 16; ++n) { p[n] = 1.0f; s[n] = 0.0f; }
    int t0 = c * LCHUNK;
    for (int tt = 0; tt < LCHUNK; ++tt) {
        size_t mrow = (size_t)(b * T_ + t0 + tt);
        float a = __half2float(amod[mrow * DIN_ + d]);
        float x = bf2f(xh[mrow * DIN_ + d]);
        const float4* bt4 = (const float4*)(Bin + mrow * 16);
        float4 q0 = bt4[0], q1 = bt4[1], q2 = bt4[2], q3 = bt4[3];
        float bt[16];
        bt[0]=q0.x; bt[1]=q0.y; bt[2]=q0.z; bt[3]=q0.w;
        bt[4]=q1.x; bt[5]=q1.y; bt[6]=q1.z; bt[7]=q1.w;
        bt[8]=q2.x; bt[9]=q2.y; bt[10]=q2.z; bt[11]=q2.w;
        bt[12]=q3.x; bt[13]=q3.y; bt[14]=q3.z; bt[15]=q3.w;
#pragma unroll
        for (int n = 0; n < 16; ++n) {
            float dk = a * ab[n];
            p[n] *= dk;
            s[n] = fmaf(dk, s[n], bt[n] * x);
        }
    }
    size_t base = ((size_t)(b * NCHUNK + c) << 15) + (size_t)d * 16;
    float4* P4 = (float4*)(P + base);
    float4* S4 = (float4*)(S + base);
#pragma unroll
    for (int j = 0; j < 4; ++j) {
        P4[j] = make_float4(p[4*j], p[4*j+1], p[4*j+2], p[4*j+3]);
        S4[j] = make_float4(s[4*j], s[4*j+1], s[4*j+2], s[4*j+3]);
    }
}

__global__ __launch_bounds__(256)
void scan_phase2(const float* __restrict__ P, const float* __restrict__ S,
                 float* __restrict__ H0) {
    int idx = blockIdx.x * 256 + threadIdx.x;   // 0..65535
    int b = idx >> 15;
    int dn = idx & 32767;
    float g = 0.f;
    for (int c = 0; c < NCHUNK; ++c) {
        size_t base = ((size_t)(b * NCHUNK + c) << 15) + dn;
        H0[base] = g;
        g = fmaf(P[base], g, S[base]);
    }
}

__global__ __launch_bounds__(256)
void scan_phase3(const __half* __restrict__ amod, const unsigned short* __restrict__ xh,
                 const float* __restrict__ Bin, const float* __restrict__ Cin,
                 const float* __restrict__ Abase, const float* __restrict__ H0,
                 const float* __restrict__ Dp, const unsigned short* __restrict__ szh,
                 unsigned short* __restrict__ yh) {
    int d = blockIdx.x * 256 + threadIdx.x;
    int c = blockIdx.y;
    int b = blockIdx.z;
    float ab[16];
#pragma unroll
    for (int n = 0; n < 16; ++n) ab[n] = sigm(Abase[n]);
    float h[16];
    size_t hbase = ((size_t)(b * NCHUNK + c) << 15) + (size_t)d * 16;
    const float4* H4 = (const float4*)(H0 + hbase);
#pragma unroll
    for (int j = 0; j < 4; ++j) {
        float4 t4 = H4[j];
        h[j*4] = t4.x; h[j*4+1] = t4.y; h[j*4+2] = t4.z; h[j*4+3] = t4.w;
    }
    float Dd = Dp[d];
    int t0 = c * LCHUNK;
    for (int tt = 0; tt < LCHUNK; ++tt) {
        size_t mrow = (size_t)(b * T_ + t0 + tt);
        float a = __half2float(amod[mrow * DIN_ + d]);
        float x = bf2f(xh[mrow * DIN_ + d]);
        const float4* bt4 = (const float4*)(Bin + mrow * 16);
        const float4* ct4 = (const float4*)(Cin + mrow * 16);
        float4 q0 = bt4[0], q1 = bt4[1], q2 = bt4[2], q3 = bt4[3];
        float4 r0 = ct4[0], r1 = ct4[1], r2 = ct4[2], r3 = ct4[3];
        float bt[16], ct[16];
        bt[0]=q0.x; bt[1]=q0.y; bt[2]=q0.z; bt[3]=q0.w;
        bt[4]=q1.x; bt[5]=q1.y; bt[6]=q1.z; bt[7]=q1.w;
        bt[8]=q2.x; bt[9]=q2.y; bt[10]=q2.z; bt[11]=q2.w;
        bt[12]=q3.x; bt[13]=q3.y; bt[14]=q3.z; bt[15]=q3.w;
        ct[0]=r0.x; ct[1]=r0.y; ct[2]=r0.z; ct[3]=r0.w;
        ct[4]=r1.x; ct[5]=r1.y; ct[6]=r1.z; ct[7]=r1.w;
        ct[8]=r2.x; ct[9]=r2.y; ct[10]=r2.z; ct[11]=r2.w;
        ct[12]=r3.x; ct[13]=r3.y; ct[14]=r3.z; ct[15]=r3.w;
        float y = 0.f;
#pragma unroll
        for (int n = 0; n < 16; ++n) {
            float dk = a * ab[n];
            h[n] = fmaf(dk, h[n], bt[n] * x);
            y = fmaf(h[n], ct[n], y);
        }
        float val = (y + Dd * x) * bf2f(szh[mrow * DIN_ + d]);
        yh[mrow * DIN_ + d] = f2bf(val);
    }
}

// ---------------- launch ----------------
extern "C" void kernel_launch(void* const* d_in, const int* in_sizes, int n_in,
                              void* d_out, int out_size, void* d_ws, size_t ws_size,
                              hipStream_t stream) {
    const float* x          = (const float*)d_in[0];
    const float* norm_w     = (const float*)d_in[1];
    const float* in_proj_w  = (const float*)d_in[2];
    const float* A_proj_w   = (const float*)d_in[3];
    const float* A_proj_b   = (const float*)d_in[4];
    const float* A_base     = (const float*)d_in[5];
    const float* B_proj_w   = (const float*)d_in[6];
    const float* C_proj_w   = (const float*)d_in[7];
    const float* Dp         = (const float*)d_in[8];
    const float* out_proj_w = (const float*)d_in[9];
    float* out = (float*)d_out;

    char* ws = (char*)d_ws;
    size_t off = 0;
    auto alloc = [&](size_t bytes) -> char* {
        char* p = ws + off;
        off += (bytes + 255) & ~(size_t)255;
        return p;
    };
    unsigned short* inT  = (unsigned short*)alloc((size_t)4096 * 1024 * 2);
    unsigned short* W2   = (unsigned short*)alloc((size_t)2048 * 2048 * 2);
    unsigned short* outT = (unsigned short*)alloc((size_t)1024 * 2048 * 2);
    unsigned short* xnh  = (unsigned short*)alloc((size_t)M_ * H_ * 2);
    unsigned short* xinh = (unsigned short*)alloc((size_t)M_ * DIN_ * 2);
    unsigned short* szh  = (unsigned short*)alloc((size_t)M_ * DIN_ * 2);
    __half* amod  = (__half*)alloc((size_t)M_ * DIN_ * 2);
    float* Bin    = (float*)alloc((size_t)M_ * 16 * 4);
    float* Cin    = (float*)alloc((size_t)M_ * 16 * 4);
    float* Pw     = (float*)alloc((size_t)B_ * NCHUNK * DIN_ * NS_ * 4);
    float* Sw     = (float*)alloc((size_t)B_ * NCHUNK * DIN_ * NS_ * 4);
    float* H0w    = (float*)alloc((size_t)B_ * NCHUNK * DIN_ * NS_ * 4);
    unsigned short* yh = (unsigned short*)alloc((size_t)M_ * DIN_ * 2);
    (void)ws_size;

    // weight prep (in/A/out transposes; B/C read directly by bc_proj)
    prep_weights<<<10240, 256, 0, stream>>>(in_proj_w, A_proj_w, out_proj_w, inT, W2, outT);

    rmsnorm_bf<<<M_, 256, 0, stream>>>(x, norm_w, xnh);

    // xz = xn @ in_proj  (M=4096, N=4096, K=1024): 256x128, BK=64 -> 512 blocks, 16 iters
    gemm_bf<0, 256, 128, 2, 4><<<dim3(4096 / 128, M_ / 256), 512, 0, stream>>>(
        xnh, inT, 1024, nullptr, xinh, szh, nullptr, nullptr);

    // a_mod = sigmoid(x_in @ A_proj + b)  (N=2048, K=2048): 256x128 -> 256 blocks, 32 iters
    gemm_bf<1, 256, 128, 2, 4><<<dim3(2048 / 128, M_ / 256), 512, 0, stream>>>(
        xinh, W2, 2048, nullptr, nullptr, nullptr, A_proj_b, amod);

    // B_in, C_in (LDS-staged weights, 16 rows/block)
    bc_proj<<<M_ / 16, 256, 0, stream>>>(xinh, B_proj_w, C_proj_w, Bin, Cin);

    // chunked scan (NCHUNK=64)
    scan_phase1<<<dim3(DIN_ / 256, NCHUNK, B_), 256, 0, stream>>>(amod, xinh, Bin, A_base, Pw, Sw);
    scan_phase2<<<(B_ * DIN_ * NS_) / 256, 256, 0, stream>>>(Pw, Sw, H0w);
    scan_phase3<<<dim3(DIN_ / 256, NCHUNK, B_), 256, 0, stream>>>(
        amod, xinh, Bin, Cin, A_base, H0w, Dp, szh, yh);

    // out = residual + y @ out_proj  (N=1024, K=2048): 128x128, BK=64 -> 256 blocks, 32 iters
    gemm_bf<2, 128, 128, 2, 4><<<dim3(1024 / 128, M_ / 128), 512, 0, stream>>>(
        yh, outT, 2048, out, nullptr, nullptr, x, nullptr);
}

// Round 11
// 230.767 us; speedup vs baseline: 1.2760x; 1.0088x over previous
//
#include <hip/hip_runtime.h>
#include <hip/hip_fp16.h>
#include <cstdint>

#define B_    2
#define T_    2048
#define H_    1024
#define DIN_  2048
#define NS_   16
#define M_    (B_*T_)     // 4096
#define NCHUNK 64
#define LCHUNK 32         // T_/NCHUNK

using bf16x8 = __attribute__((ext_vector_type(8))) short;
using f32x4  = __attribute__((ext_vector_type(4))) float;

__device__ __forceinline__ unsigned short f2bf(float f) {
    union { float f; uint32_t u; } x; x.f = f;
    uint32_t u = x.u;
    uint32_t r = (u + 0x7fffu + ((u >> 16) & 1u)) >> 16;
    return (unsigned short)r;
}
__device__ __forceinline__ float bf2f(unsigned short h) {
    union { uint32_t u; float f; } x; x.u = ((uint32_t)h) << 16;
    return x.f;
}
__device__ __forceinline__ float sigm(float v) { return 1.0f / (1.0f + expf(-v)); }
__device__ __forceinline__ float silu(float v) { return v / (1.0f + expf(-v)); }

__device__ __forceinline__ void gload_lds16(const void* g, void* l) {
    __builtin_amdgcn_global_load_lds(
        (__attribute__((address_space(1))) void*)(void*)g,
        (__attribute__((address_space(3))) void*)l, 16, 0, 0);
}

// ---------------- fused weight prep: transposes to bf16 [N][K] ----------------
__global__ __launch_bounds__(256)
void prep_weights(const float* __restrict__ in_proj, const float* __restrict__ A_proj,
                  const float* __restrict__ out_proj,
                  unsigned short* __restrict__ inT, unsigned short* __restrict__ W2,
                  unsigned short* __restrict__ outT) {
    int bid = blockIdx.x;
    int tid = threadIdx.x;
    const float* src; unsigned short* dst; int K, N, l;
    if (bid < 4096)      { src = in_proj;  dst = inT;  K = 1024; N = 4096; l = bid; }
    else if (bid < 8192) { src = A_proj;   dst = W2;   K = 2048; N = 2048; l = bid - 4096; }
    else                 { src = out_proj; dst = outT; K = 2048; N = 1024; l = bid - 8192; }
    int ntiles = N >> 5;
    int n0 = (l % ntiles) * 32, k0 = (l / ntiles) * 32;
    __shared__ float tile[32][33];
    int tx = tid & 31, ty = tid >> 5;   // ty 0..7
#pragma unroll
    for (int i = 0; i < 32; i += 8)
        tile[ty + i][tx] = src[(size_t)(k0 + ty + i) * N + (n0 + tx)];
    __syncthreads();
    int sx = (tid & 15) * 2;   // k offset, even
    int sy = tid >> 4;         // n 0..15
#pragma unroll
    for (int i = 0; i < 32; i += 16) {
        int n = sy + i;
        float v0 = tile[sx][n], v1 = tile[sx + 1][n];
        size_t o = (size_t)(n0 + n) * K + (k0 + sx);
        *(ushort2*)&dst[o] = make_ushort2(f2bf(v0), f2bf(v1));
    }
}

// ---------------- RMSNorm -> single bf16 ----------------
__global__ __launch_bounds__(256)
void rmsnorm_bf(const float* __restrict__ x, const float* __restrict__ w,
                unsigned short* __restrict__ xh) {
    int row = blockIdx.x;            // 0..4095
    int tid = threadIdx.x;
    const float4* xr = (const float4*)(x + (size_t)row * H_);
    float4 v = xr[tid];
    float ss = v.x * v.x + v.y * v.y + v.z * v.z + v.w * v.w;
#pragma unroll
    for (int o = 32; o > 0; o >>= 1) ss += __shfl_down(ss, o, 64);
    __shared__ float red[4];
    int lane = tid & 63, wv = tid >> 6;
    if (lane == 0) red[wv] = ss;
    __syncthreads();
    float tot = red[0] + red[1] + red[2] + red[3];
    float rstd = rsqrtf(tot / (float)H_ + 1e-6f);
    const float4* wr = (const float4*)w;
    float4 w4 = wr[tid];
    size_t o = (size_t)row * H_ + tid * 4;
    *(ushort4*)&xh[o] = make_ushort4(f2bf(v.x * rstd * w4.x), f2bf(v.y * rstd * w4.y),
                                     f2bf(v.z * rstd * w4.z), f2bf(v.w * rstd * w4.w));
}

// ---------------- 8-phase bf16 GEMM (m201-template port): C = A @ B^T ----------------
// BM x BN tile, BK=64, 8 waves (2M x 4N), 2 K-tile LDS buffers (parity).
// Per K-tile: 2*PH phases, each {barrier -> ds_read frags || stage SPP units of
// tile kt+1 -> lgkmcnt(0) -> setprio MFMA cluster}. vmcnt(SPG) at ks-boundaries only
// (counted, never 0 mid-loop); staged->use slack 3-4 phases. Race-free: stages target
// the idle parity buffer; barrier lockstep + per-phase lgkm ensures reads precede
// overwrites. Unit = 16 rows x 32k (1KB), r5-proven XOR swizzle (0 conflicts).
// EPI 0: xz -> silu (x_in bf16 / silu_z bf16); EPI 1: a_mod fp16; EPI 2: out + residual.
template <int EPI, int BM, int BN>
__global__ __launch_bounds__(512, (BM == 128) ? 4 : 2)
void gemm8p(const unsigned short* __restrict__ Aa, const unsigned short* __restrict__ Bw,
            int K,
            float* __restrict__ out0,
            unsigned short* __restrict__ oh, unsigned short* __restrict__ oz,
            const float* __restrict__ aux, __half* __restrict__ oha) {
    constexpr int AU   = (BM / 16) * 2;      // A units per K-tile (16r x 32k each)
    constexpr int BU   = (BN / 16) * 2;
    constexpr int BUFU = AU + BU;            // units per buffer
    constexpr int MF   = BM / 2 / 16;        // per-wave m-frags
    constexpr int NF   = BN / 4 / 16;        // per-wave n-frags
    constexpr int PH   = (NF == 4) ? 2 : 1;  // phases per ks
    constexpr int NP   = NF / PH;            // n-frags per phase
    constexpr int SPWK = BUFU / 8;           // stage units / wave / K-tile
    constexpr int SPG  = SPWK / 2;           // per ks-group (= vmcnt count)
    constexpr int SPP  = SPG / PH;           // per phase
    __shared__ unsigned short sm[2 * BUFU * 512];
    const int tid  = threadIdx.x;
    const int lane = tid & 63;
    const int wid  = tid >> 6;
    const int wm   = wid >> 2;               // 0..1
    const int wn   = wid & 3;                // 0..3

    // XCD-chunked bijective block swizzle (grid %8 == 0)
    const int gx   = gridDim.x;
    const int nwg  = gx * gridDim.y;
    const int orig = blockIdx.y * gx + blockIdx.x;
    const int qq   = nwg >> 3;
    const int lid  = (orig & 7) * qq + (orig >> 3);
    const int bm   = (lid / gx) * BM;
    const int bn   = (lid % gx) * BN;

    // staging map: lane -> row lane>>2, source granule swizzled within 64B row
    const int srow  = lane >> 2;
    const int sgran = (lane & 3) ^ ((lane >> 3) & 3);
    // per-wave stage list: group ks=0 units first (oldest), then ks=1; A-chunks then B
    const unsigned short* gpp[SPWK];
    int lofs_[SPWK];
#pragma unroll
    for (int g = 0; g < 2; ++g)
#pragma unroll
        for (int i = 0; i < SPG; ++i) {
            int cn = wid * SPG + i;          // chunk index within group
            const unsigned short* src;
            int u;
            if (cn < AU / 2) { u = cn * 2 + g;             src = Aa + (size_t)(bm + cn * 16 + srow) * K; }
            else { int bc = cn - AU / 2; u = AU + bc * 2 + g; src = Bw + (size_t)(bn + bc * 16 + srow) * K; }
            gpp[g * SPG + i]   = src + g * 32 + sgran * 8;
            lofs_[g * SPG + i] = u * 512;
        }

    const int nt = K >> 6;
    // prologue: stage tile 0 (group order: ks0 oldest)
#pragma unroll
    for (int j = 0; j < SPWK; ++j) gload_lds16(gpp[j], &sm[lofs_[j]]);

    // frag read offset (ushorts) within a unit: r5-proven swizzle
    const int fro = (lane & 15) * 32 + (((lane >> 4) ^ ((lane >> 1) & 3)) * 8);

    f32x4 acc[MF][NF] = {};
    for (int kt = 0; kt < nt; ++kt) {
        const unsigned short* sb = &sm[(kt & 1) * (BUFU * 512)];
        unsigned short*       db = &sm[((kt + 1) & 1) * (BUFU * 512)];
        const bool pf = (kt + 1 < nt);
        bf16x8 af[MF];
#pragma unroll
        for (int ks = 0; ks < 2; ++ks) {
            // ks-boundary: counted vmcnt (oldest ks-group of tile kt retired)
            if (ks == 1 && kt == nt - 1) {
                asm volatile("s_waitcnt vmcnt(0)" ::: "memory");
            } else {
                if constexpr (SPG == 4)      asm volatile("s_waitcnt vmcnt(4)" ::: "memory");
                else if constexpr (SPG == 3) asm volatile("s_waitcnt vmcnt(3)" ::: "memory");
                else                         asm volatile("s_waitcnt vmcnt(2)" ::: "memory");
            }
            __builtin_amdgcn_s_barrier();
            __builtin_amdgcn_sched_barrier(0);
#pragma unroll
            for (int ph = 0; ph < PH; ++ph) {
                if (ph) {
                    __builtin_amdgcn_s_barrier();
                    __builtin_amdgcn_sched_barrier(0);
                }
                if (ph == 0) {
#pragma unroll
                    for (int mf = 0; mf < MF; ++mf)
                        af[mf] = *(const bf16x8*)&sb[((wm * MF + mf) * 2 + ks) * 512 + fro];
                }
                bf16x8 bf8[NP];
#pragma unroll
                for (int j = 0; j < NP; ++j) {
                    int nfg = ph * NP + j;
                    bf8[j] = *(const bf16x8*)&sb[(AU + (wn * NF + nfg) * 2 + ks) * 512 + fro];
                }
                if (pf) {
#pragma unroll
                    for (int j = 0; j < SPP; ++j) {
                        int s = (ks * PH + ph) * SPP + j;
                        gload_lds16(gpp[s] + (size_t)(kt + 1) * 64, db + lofs_[s]);
                    }
                }
                asm volatile("s_waitcnt lgkmcnt(0)" ::: "memory");
                __builtin_amdgcn_sched_barrier(0);
                __builtin_amdgcn_s_setprio(1);
#pragma unroll
                for (int mf = 0; mf < MF; ++mf)
#pragma unroll
                    for (int j = 0; j < NP; ++j)
                        acc[mf][ph * NP + j] = __builtin_amdgcn_mfma_f32_16x16x32_bf16(
                            af[mf], bf8[j], acc[mf][ph * NP + j], 0, 0, 0);
                __builtin_amdgcn_s_setprio(0);
            }
        }
    }

    // epilogue: C/D layout col=lane&15, row=(lane>>4)*4+reg  [m89-verified]
#pragma unroll
    for (int mf = 0; mf < MF; ++mf)
#pragma unroll
        for (int nf = 0; nf < NF; ++nf) {
            int col  = bn + (wn * NF + nf) * 16 + (lane & 15);
            int row0 = bm + (wm * MF + mf) * 16 + ((lane >> 4) << 2);
#pragma unroll
            for (int r = 0; r < 4; ++r) {
                int row = row0 + r;
                float v = acc[mf][nf][r];
                if (EPI == 0) {
                    float s = silu(v);
                    if (col < DIN_) oh[(size_t)row * DIN_ + col] = f2bf(s);
                    else            oz[(size_t)row * DIN_ + (col - DIN_)] = f2bf(s);
                } else if (EPI == 1) {
                    oha[(size_t)row * DIN_ + col] = __float2half(sigm(v + aux[col]));
                } else {
                    out0[(size_t)row * H_ + col] = v + aux[(size_t)row * H_ + col];
                }
            }
        }
}

// ---------------- B_in / C_in projections, LDS-staged weights ----------------
#define KT_ 512
__global__ __launch_bounds__(256)
void bc_proj(const unsigned short* __restrict__ xh,
             const float* __restrict__ Bw, const float* __restrict__ Cw,
             float* __restrict__ Bout, float* __restrict__ Cout) {
    __shared__ float wB[KT_][17];
    __shared__ float wC[KT_][17];
    const int m0  = blockIdx.x * 16;
    const int tid = threadIdx.x;
    const int r   = tid >> 4;      // 0..15 row within block
    const int j   = tid & 15;      // k-lane
    float ab[16], ac[16];
#pragma unroll
    for (int i = 0; i < 16; ++i) { ab[i] = 0.f; ac[i] = 0.f; }

    for (int kt = 0; kt < DIN_; kt += KT_) {
        if (kt) __syncthreads();
        const float4* bs = (const float4*)(Bw + (size_t)kt * 16);
        const float4* cs = (const float4*)(Cw + (size_t)kt * 16);
#pragma unroll
        for (int i = 0; i < 8; ++i) {
            int idx = i * 256 + tid;
            int kk = idx >> 2, c4 = (idx & 3) * 4;
            float4 vb = bs[idx], vc = cs[idx];
            wB[kk][c4 + 0] = vb.x; wB[kk][c4 + 1] = vb.y; wB[kk][c4 + 2] = vb.z; wB[kk][c4 + 3] = vb.w;
            wC[kk][c4 + 0] = vc.x; wC[kk][c4 + 1] = vc.y; wC[kk][c4 + 2] = vc.z; wC[kk][c4 + 3] = vc.w;
        }
        __syncthreads();
        const unsigned short* xr = xh + (size_t)(m0 + r) * DIN_ + kt;
#pragma unroll 4
        for (int kk = 0; kk < 32; ++kk) {
            int kl = kk * 16 + j;
            float x = bf2f(xr[kl]);
#pragma unroll
            for (int c = 0; c < 16; ++c) {
                ab[c] = fmaf(x, wB[kl][c], ab[c]);
                ac[c] = fmaf(x, wC[kl][c], ac[c]);
            }
        }
    }
#pragma unroll
    for (int i = 0; i < 16; ++i) {
#pragma unroll
        for (int m = 8; m > 0; m >>= 1) {
            ab[i] += __shfl_xor(ab[i], m, 64);
            ac[i] += __shfl_xor(ac[i], m, 64);
        }
    }
    if (j == 0) {
#pragma unroll
        for (int i = 0; i < 16; ++i) {
            Bout[(size_t)(m0 + r) * 16 + i] = ab[i];
            Cout[(size_t)(m0 + r) * 16 + i] = ac[i];
        }
    }
}

// ---------------- chunked parallel scan ----------------
__global__ __launch_bounds__(256)
void scan_phase1(const __half* __restrict__ amod, const unsigned short* __restrict__ xh,
                 const float* __restrict__ Bin, const float* __restrict__ Abase,
                 float* __restrict__ P, float* __restrict__ S) {
    int d = blockIdx.x * 256 + threadIdx.x;   // 0..2047
    int c = blockIdx.y;
    int b = blockIdx.z;
    float ab[16];
#pragma unroll
    for (int n = 0; n < 16; ++n) ab[n] = sigm(Abase[n]);
    float p[16], s[16];
#pragma unroll
    for (int n = 0; n < 16; ++n) { p[n] = 1.0f; s[n] = 0.0f; }
    int t0 = c * LCHUNK;
    for (int tt = 0; tt < LCHUNK; ++tt) {
        size_t mrow = (size_t)(b * T_ + t0 + tt);
        float a = __half2float(amod[mrow * DIN_ + d]);
        float x = bf2f(xh[mrow * DIN_ + d]);
        const float4* bt4 = (const float4*)(Bin + mrow * 16);
        float4 q0 = bt4[0], q1 = bt4[1], q2 = bt4[2], q3 = bt4[3];
        float bt[16];
        bt[0]=q0.x; bt[1]=q0.y; bt[2]=q0.z; bt[3]=q0.w;
        bt[4]=q1.x; bt[5]=q1.y; bt[6]=q1.z; bt[7]=q1.w;
        bt[8]=q2.x; bt[9]=q2.y; bt[10]=q2.z; bt[11]=q2.w;
        bt[12]=q3.x; bt[13]=q3.y; bt[14]=q3.z; bt[15]=q3.w;
#pragma unroll
        for (int n = 0; n < 16; ++n) {
            float dk = a * ab[n];
            p[n] *= dk;
            s[n] = fmaf(dk, s[n], bt[n] * x);
        }
    }
    size_t base = ((size_t)(b * NCHUNK + c) << 15) + (size_t)d * 16;
    float4* P4 = (float4*)(P + base);
    float4* S4 = (float4*)(S + base);
#pragma unroll
    for (int j = 0; j < 4; ++j) {
        P4[j] = make_float4(p[4*j], p[4*j+1], p[4*j+2], p[4*j+3]);
        S4[j] = make_float4(s[4*j], s[4*j+1], s[4*j+2], s[4*j+3]);
    }
}

__global__ __launch_bounds__(256)
void scan_phase2(const float* __restrict__ P, const float* __restrict__ S,
                 float* __restrict__ H0) {
    int idx = blockIdx.x * 256 + threadIdx.x;   // 0..65535
    int b = idx >> 15;
    int dn = idx & 32767;
    float g = 0.f;
    for (int c = 0; c < NCHUNK; ++c) {
        size_t base = ((size_t)(b * NCHUNK + c) << 15) + dn;
        H0[base] = g;
        g = fmaf(P[base], g, S[base]);
    }
}

__global__ __launch_bounds__(256)
void scan_phase3(const __half* __restrict__ amod, const unsigned short* __restrict__ xh,
                 const float* __restrict__ Bin, const float* __restrict__ Cin,
                 const float* __restrict__ Abase, const float* __restrict__ H0,
                 const float* __restrict__ Dp, const unsigned short* __restrict__ szh,
                 unsigned short* __restrict__ yh) {
    int d = blockIdx.x * 256 + threadIdx.x;
    int c = blockIdx.y;
    int b = blockIdx.z;
    float ab[16];
#pragma unroll
    for (int n = 0; n < 16; ++n) ab[n] = sigm(Abase[n]);
    float h[16];
    size_t hbase = ((size_t)(b * NCHUNK + c) << 15) + (size_t)d * 16;
    const float4* H4 = (const float4*)(H0 + hbase);
#pragma unroll
    for (int j = 0; j < 4; ++j) {
        float4 t4 = H4[j];
        h[j*4] = t4.x; h[j*4+1] = t4.y; h[j*4+2] = t4.z; h[j*4+3] = t4.w;
    }
    float Dd = Dp[d];
    int t0 = c * LCHUNK;
    for (int tt = 0; tt < LCHUNK; ++tt) {
        size_t mrow = (size_t)(b * T_ + t0 + tt);
        float a = __half2float(amod[mrow * DIN_ + d]);
        float x = bf2f(xh[mrow * DIN_ + d]);
        const float4* bt4 = (const float4*)(Bin + mrow * 16);
        const float4* ct4 = (const float4*)(Cin + mrow * 16);
        float4 q0 = bt4[0], q1 = bt4[1], q2 = bt4[2], q3 = bt4[3];
        float4 r0 = ct4[0], r1 = ct4[1], r2 = ct4[2], r3 = ct4[3];
        float bt[16], ct[16];
        bt[0]=q0.x; bt[1]=q0.y; bt[2]=q0.z; bt[3]=q0.w;
        bt[4]=q1.x; bt[5]=q1.y; bt[6]=q1.z; bt[7]=q1.w;
        bt[8]=q2.x; bt[9]=q2.y; bt[10]=q2.z; bt[11]=q2.w;
        bt[12]=q3.x; bt[13]=q3.y; bt[14]=q3.z; bt[15]=q3.w;
        ct[0]=r0.x; ct[1]=r0.y; ct[2]=r0.z; ct[3]=r0.w;
        ct[4]=r1.x; ct[5]=r1.y; ct[6]=r1.z; ct[7]=r1.w;
        ct[8]=r2.x; ct[9]=r2.y; ct[10]=r2.z; ct[11]=r2.w;
        ct[12]=r3.x; ct[13]=r3.y; ct[14]=r3.z; ct[15]=r3.w;
        float y = 0.f;
#pragma unroll
        for (int n = 0; n < 16; ++n) {
            float dk = a * ab[n];
            h[n] = fmaf(dk, h[n], bt[n] * x);
            y = fmaf(h[n], ct[n], y);
        }
        float val = (y + Dd * x) * bf2f(szh[mrow * DIN_ + d]);
        yh[mrow * DIN_ + d] = f2bf(val);
    }
}

// ---------------- launch ----------------
extern "C" void kernel_launch(void* const* d_in, const int* in_sizes, int n_in,
                              void* d_out, int out_size, void* d_ws, size_t ws_size,
                              hipStream_t stream) {
    const float* x          = (const float*)d_in[0];
    const float* norm_w     = (const float*)d_in[1];
    const float* in_proj_w  = (const float*)d_in[2];
    const float* A_proj_w   = (const float*)d_in[3];
    const float* A_proj_b   = (const float*)d_in[4];
    const float* A_base     = (const float*)d_in[5];
    const float* B_proj_w   = (const float*)d_in[6];
    const float* C_proj_w   = (const float*)d_in[7];
    const float* Dp         = (const float*)d_in[8];
    const float* out_proj_w = (const float*)d_in[9];
    float* out = (float*)d_out;

    char* ws = (char*)d_ws;
    size_t off = 0;
    auto alloc = [&](size_t bytes) -> char* {
        char* p = ws + off;
        off += (bytes + 255) & ~(size_t)255;
        return p;
    };
    unsigned short* inT  = (unsigned short*)alloc((size_t)4096 * 1024 * 2);
    unsigned short* W2   = (unsigned short*)alloc((size_t)2048 * 2048 * 2);
    unsigned short* outT = (unsigned short*)alloc((size_t)1024 * 2048 * 2);
    unsigned short* xnh  = (unsigned short*)alloc((size_t)M_ * H_ * 2);
    unsigned short* xinh = (unsigned short*)alloc((size_t)M_ * DIN_ * 2);
    unsigned short* szh  = (unsigned short*)alloc((size_t)M_ * DIN_ * 2);
    __half* amod  = (__half*)alloc((size_t)M_ * DIN_ * 2);
    float* Bin    = (float*)alloc((size_t)M_ * 16 * 4);
    float* Cin    = (float*)alloc((size_t)M_ * 16 * 4);
    float* Pw     = (float*)alloc((size_t)B_ * NCHUNK * DIN_ * NS_ * 4);
    float* Sw     = (float*)alloc((size_t)B_ * NCHUNK * DIN_ * NS_ * 4);
    float* H0w    = (float*)alloc((size_t)B_ * NCHUNK * DIN_ * NS_ * 4);
    unsigned short* yh = (unsigned short*)alloc((size_t)M_ * DIN_ * 2);
    (void)ws_size;

    // weight prep (in/A/out transposes; B/C read directly by bc_proj)
    prep_weights<<<10240, 256, 0, stream>>>(in_proj_w, A_proj_w, out_proj_w, inT, W2, outT);

    rmsnorm_bf<<<M_, 256, 0, stream>>>(x, norm_w, xnh);

    // xz = xn @ in_proj  (M=4096, N=4096, K=1024): 256x256 8-phase -> 256 blocks, nt=16
    gemm8p<0, 256, 256><<<dim3(4096 / 256, M_ / 256), 512, 0, stream>>>(
        xnh, inT, 1024, nullptr, xinh, szh, nullptr, nullptr);

    // a_mod = sigmoid(x_in @ A_proj + b)  (N=2048, K=2048): 256x128 -> 256 blocks, nt=32
    gemm8p<1, 256, 128><<<dim3(2048 / 128, M_ / 256), 512, 0, stream>>>(
        xinh, W2, 2048, nullptr, nullptr, nullptr, A_proj_b, amod);

    // B_in, C_in (LDS-staged weights, 16 rows/block)
    bc_proj<<<M_ / 16, 256, 0, stream>>>(xinh, B_proj_w, C_proj_w, Bin, Cin);

    // chunked scan (NCHUNK=64)
    scan_phase1<<<dim3(DIN_ / 256, NCHUNK, B_), 256, 0, stream>>>(amod, xinh, Bin, A_base, Pw, Sw);
    scan_phase2<<<(B_ * DIN_ * NS_) / 256, 256, 0, stream>>>(Pw, Sw, H0w);
    scan_phase3<<<dim3(DIN_ / 256, NCHUNK, B_), 256, 0, stream>>>(
        amod, xinh, Bin, Cin, A_base, H0w, Dp, szh, yh);

    // out = residual + y @ out_proj  (N=1024, K=2048): 128x128 -> 256 blocks (2/CU), nt=32
    gemm8p<2, 128, 128><<<dim3(1024 / 128, M_ / 128), 512, 0, stream>>>(
        yh, outT, 2048, out, nullptr, nullptr, x, nullptr);
}

// Round 12
// 229.105 us; speedup vs baseline: 1.2853x; 1.0073x over previous
//
#include <hip/hip_runtime.h>
#include <hip/hip_fp16.h>
#include <cstdint>

#define B_    2
#define T_    2048
#define H_    1024
#define DIN_  2048
#define NS_   16
#define M_    (B_*T_)     // 4096
#define NCHUNK 64
#define LCHUNK 32         // T_/NCHUNK

using bf16x8 = __attribute__((ext_vector_type(8))) short;
using f32x4  = __attribute__((ext_vector_type(4))) float;

__device__ __forceinline__ unsigned short f2bf(float f) {
    union { float f; uint32_t u; } x; x.f = f;
    uint32_t u = x.u;
    uint32_t r = (u + 0x7fffu + ((u >> 16) & 1u)) >> 16;
    return (unsigned short)r;
}
__device__ __forceinline__ float bf2f(unsigned short h) {
    union { uint32_t u; float f; } x; x.u = ((uint32_t)h) << 16;
    return x.f;
}
__device__ __forceinline__ float sigm(float v) { return 1.0f / (1.0f + expf(-v)); }
__device__ __forceinline__ float silu(float v) { return v / (1.0f + expf(-v)); }

__device__ __forceinline__ void gload_lds16(const void* g, void* l) {
    __builtin_amdgcn_global_load_lds(
        (__attribute__((address_space(1))) void*)(void*)g,
        (__attribute__((address_space(3))) void*)l, 16, 0, 0);
}

// ---------------- fused prep: weight transposes + RMSNorm in one launch ----------------
// [0,4096) in_proj -> inT; [4096,8192) A_proj -> W2; [8192,10240) out_proj -> outT;
// [10240,14336) rmsnorm row (bid-10240) -> xnh
__global__ __launch_bounds__(256)
void prep_all(const float* __restrict__ in_proj, const float* __restrict__ A_proj,
              const float* __restrict__ out_proj,
              const float* __restrict__ x, const float* __restrict__ norm_w,
              unsigned short* __restrict__ inT, unsigned short* __restrict__ W2,
              unsigned short* __restrict__ outT, unsigned short* __restrict__ xnh) {
    int bid = blockIdx.x;
    int tid = threadIdx.x;
    __shared__ float tile[32][33];
    __shared__ float red[4];
    if (bid >= 10240) {      // RMSNorm rows
        int row = bid - 10240;
        const float4* xr = (const float4*)(x + (size_t)row * H_);
        float4 v = xr[tid];
        float ss = v.x * v.x + v.y * v.y + v.z * v.z + v.w * v.w;
#pragma unroll
        for (int o = 32; o > 0; o >>= 1) ss += __shfl_down(ss, o, 64);
        int lane = tid & 63, wv = tid >> 6;
        if (lane == 0) red[wv] = ss;
        __syncthreads();
        float tot = red[0] + red[1] + red[2] + red[3];
        float rstd = rsqrtf(tot / (float)H_ + 1e-6f);
        const float4* wr = (const float4*)norm_w;
        float4 w4 = wr[tid];
        size_t o = (size_t)row * H_ + tid * 4;
        *(ushort4*)&xnh[o] = make_ushort4(f2bf(v.x * rstd * w4.x), f2bf(v.y * rstd * w4.y),
                                          f2bf(v.z * rstd * w4.z), f2bf(v.w * rstd * w4.w));
        return;
    }
    const float* src; unsigned short* dst; int K, N, l;
    if (bid < 4096)      { src = in_proj;  dst = inT;  K = 1024; N = 4096; l = bid; }
    else if (bid < 8192) { src = A_proj;   dst = W2;   K = 2048; N = 2048; l = bid - 4096; }
    else                 { src = out_proj; dst = outT; K = 2048; N = 1024; l = bid - 8192; }
    int ntiles = N >> 5;
    int n0 = (l % ntiles) * 32, k0 = (l / ntiles) * 32;
    int tx = tid & 31, ty = tid >> 5;   // ty 0..7
#pragma unroll
    for (int i = 0; i < 32; i += 8)
        tile[ty + i][tx] = src[(size_t)(k0 + ty + i) * N + (n0 + tx)];
    __syncthreads();
    int sx = (tid & 15) * 2;   // k offset, even
    int sy = tid >> 4;         // n 0..15
#pragma unroll
    for (int i = 0; i < 32; i += 16) {
        int n = sy + i;
        float v0 = tile[sx][n], v1 = tile[sx + 1][n];
        size_t o = (size_t)(n0 + n) * K + (k0 + sx);
        *(ushort2*)&dst[o] = make_ushort2(f2bf(v0), f2bf(v1));
    }
}

// ---------------- 8-phase bf16 GEMM: C = A @ B^T ----------------
// BM x BN tile, BK=64, 8 waves (2M x 4N), 2 K-tile LDS buffers (parity).
// Per K-tile: 2*PH phases {barrier -> ds_read frags || stage SPP units of kt+1 ||
// MFMA cluster (compiler-scheduled: fine-grained lgkm interleave — r12 removed the
// lgkmcnt(0) pin, the r11 serialization)}. vmcnt(SPG) at ks boundaries only.
// Race-free: stage targets idle parity buffer; each s_barrier + sched_barrier(0)
// pins code motion at sync points. Unit = 16r x 32k (1KB), r5-proven XOR swizzle.
// EPI 0: xz -> silu (x_in bf16 / silu_z bf16); EPI 1: a_mod fp16; EPI 2: out + residual.
template <int EPI, int BM, int BN>
__global__ __launch_bounds__(512, (BM == 128) ? 4 : 2)
void gemm8p(const unsigned short* __restrict__ Aa, const unsigned short* __restrict__ Bw,
            int K,
            float* __restrict__ out0,
            unsigned short* __restrict__ oh, unsigned short* __restrict__ oz,
            const float* __restrict__ aux, __half* __restrict__ oha) {
    constexpr int AU   = (BM / 16) * 2;      // A units per K-tile (16r x 32k each)
    constexpr int BU   = (BN / 16) * 2;
    constexpr int BUFU = AU + BU;            // units per buffer
    constexpr int MF   = BM / 2 / 16;        // per-wave m-frags
    constexpr int NF   = BN / 4 / 16;        // per-wave n-frags
    constexpr int PH   = (NF == 4) ? 2 : 1;  // phases per ks
    constexpr int NP   = NF / PH;            // n-frags per phase
    constexpr int SPWK = BUFU / 8;           // stage units / wave / K-tile
    constexpr int SPG  = SPWK / 2;           // per ks-group (= vmcnt count)
    constexpr int SPP  = SPG / PH;           // per phase
    __shared__ unsigned short sm[2 * BUFU * 512];
    const int tid  = threadIdx.x;
    const int lane = tid & 63;
    const int wid  = tid >> 6;
    const int wm   = wid >> 2;               // 0..1
    const int wn   = wid & 3;                // 0..3

    // XCD-chunked bijective block swizzle (grid %8 == 0)
    const int gx   = gridDim.x;
    const int nwg  = gx * gridDim.y;
    const int orig = blockIdx.y * gx + blockIdx.x;
    const int qq   = nwg >> 3;
    const int lid  = (orig & 7) * qq + (orig >> 3);
    const int bm   = (lid / gx) * BM;
    const int bn   = (lid % gx) * BN;

    // staging map: lane -> row lane>>2, source granule swizzled within 64B row
    const int srow  = lane >> 2;
    const int sgran = (lane & 3) ^ ((lane >> 3) & 3);
    const unsigned short* gpp[SPWK];
    int lofs_[SPWK];
#pragma unroll
    for (int g = 0; g < 2; ++g)
#pragma unroll
        for (int i = 0; i < SPG; ++i) {
            int cn = wid * SPG + i;          // chunk index within group
            const unsigned short* src;
            int u;
            if (cn < AU / 2) { u = cn * 2 + g;             src = Aa + (size_t)(bm + cn * 16 + srow) * K; }
            else { int bc = cn - AU / 2; u = AU + bc * 2 + g; src = Bw + (size_t)(bn + bc * 16 + srow) * K; }
            gpp[g * SPG + i]   = src + g * 32 + sgran * 8;
            lofs_[g * SPG + i] = u * 512;
        }

    const int nt = K >> 6;
    // prologue: stage tile 0 (group order: ks0 oldest)
#pragma unroll
    for (int j = 0; j < SPWK; ++j) gload_lds16(gpp[j], &sm[lofs_[j]]);

    // frag read offset (ushorts) within a unit: r5-proven swizzle
    const int fro = (lane & 15) * 32 + (((lane >> 4) ^ ((lane >> 1) & 3)) * 8);

    f32x4 acc[MF][NF] = {};
    for (int kt = 0; kt < nt; ++kt) {
        const unsigned short* sb = &sm[(kt & 1) * (BUFU * 512)];
        unsigned short*       db = &sm[((kt + 1) & 1) * (BUFU * 512)];
        const bool pf = (kt + 1 < nt);
        bf16x8 af[MF];
#pragma unroll
        for (int ks = 0; ks < 2; ++ks) {
            // ks-boundary: counted vmcnt (oldest ks-group of tile kt retired)
            if (ks == 1 && kt == nt - 1) {
                asm volatile("s_waitcnt vmcnt(0)" ::: "memory");
            } else {
                if constexpr (SPG == 4)      asm volatile("s_waitcnt vmcnt(4)" ::: "memory");
                else if constexpr (SPG == 3) asm volatile("s_waitcnt vmcnt(3)" ::: "memory");
                else                         asm volatile("s_waitcnt vmcnt(2)" ::: "memory");
            }
            __builtin_amdgcn_s_barrier();
            __builtin_amdgcn_sched_barrier(0);
#pragma unroll
            for (int ph = 0; ph < PH; ++ph) {
                if (ph) {
                    __builtin_amdgcn_s_barrier();
                    __builtin_amdgcn_sched_barrier(0);
                }
                if (ph == 0) {
#pragma unroll
                    for (int mf = 0; mf < MF; ++mf)
                        af[mf] = *(const bf16x8*)&sb[((wm * MF + mf) * 2 + ks) * 512 + fro];
                }
                bf16x8 bf8[NP];
#pragma unroll
                for (int j = 0; j < NP; ++j) {
                    int nfg = ph * NP + j;
                    bf8[j] = *(const bf16x8*)&sb[(AU + (wn * NF + nfg) * 2 + ks) * 512 + fro];
                }
                if (pf) {
#pragma unroll
                    for (int j = 0; j < SPP; ++j) {
                        int s = (ks * PH + ph) * SPP + j;
                        gload_lds16(gpp[s] + (size_t)(kt + 1) * 64, db + lofs_[s]);
                    }
                }
                // r12: no lgkm pin here — compiler interleaves ds_reads under MFMAs
                __builtin_amdgcn_s_setprio(1);
#pragma unroll
                for (int mf = 0; mf < MF; ++mf)
#pragma unroll
                    for (int j = 0; j < NP; ++j)
                        acc[mf][ph * NP + j] = __builtin_amdgcn_mfma_f32_16x16x32_bf16(
                            af[mf], bf8[j], acc[mf][ph * NP + j], 0, 0, 0);
                __builtin_amdgcn_s_setprio(0);
            }
        }
    }

    // epilogue: C/D layout col=lane&15, row=(lane>>4)*4+reg  [m89-verified]
#pragma unroll
    for (int mf = 0; mf < MF; ++mf)
#pragma unroll
        for (int nf = 0; nf < NF; ++nf) {
            int col  = bn + (wn * NF + nf) * 16 + (lane & 15);
            int row0 = bm + (wm * MF + mf) * 16 + ((lane >> 4) << 2);
#pragma unroll
            for (int r = 0; r < 4; ++r) {
                int row = row0 + r;
                float v = acc[mf][nf][r];
                if (EPI == 0) {
                    float s = silu(v);
                    if (col < DIN_) oh[(size_t)row * DIN_ + col] = f2bf(s);
                    else            oz[(size_t)row * DIN_ + (col - DIN_)] = f2bf(s);
                } else if (EPI == 1) {
                    oha[(size_t)row * DIN_ + col] = __float2half(sigm(v + aux[col]));
                } else {
                    out0[(size_t)row * H_ + col] = v + aux[(size_t)row * H_ + col];
                }
            }
        }
}

// ---------------- B_in / C_in projections, LDS-staged weights ----------------
#define KT_ 512
__global__ __launch_bounds__(256)
void bc_proj(const unsigned short* __restrict__ xh,
             const float* __restrict__ Bw, const float* __restrict__ Cw,
             float* __restrict__ Bout, float* __restrict__ Cout) {
    __shared__ float wB[KT_][17];
    __shared__ float wC[KT_][17];
    const int m0  = blockIdx.x * 16;
    const int tid = threadIdx.x;
    const int r   = tid >> 4;      // 0..15 row within block
    const int j   = tid & 15;      // k-lane
    float ab[16], ac[16];
#pragma unroll
    for (int i = 0; i < 16; ++i) { ab[i] = 0.f; ac[i] = 0.f; }

    for (int kt = 0; kt < DIN_; kt += KT_) {
        if (kt) __syncthreads();
        const float4* bs = (const float4*)(Bw + (size_t)kt * 16);
        const float4* cs = (const float4*)(Cw + (size_t)kt * 16);
#pragma unroll
        for (int i = 0; i < 8; ++i) {
            int idx = i * 256 + tid;
            int kk = idx >> 2, c4 = (idx & 3) * 4;
            float4 vb = bs[idx], vc = cs[idx];
            wB[kk][c4 + 0] = vb.x; wB[kk][c4 + 1] = vb.y; wB[kk][c4 + 2] = vb.z; wB[kk][c4 + 3] = vb.w;
            wC[kk][c4 + 0] = vc.x; wC[kk][c4 + 1] = vc.y; wC[kk][c4 + 2] = vc.z; wC[kk][c4 + 3] = vc.w;
        }
        __syncthreads();
        const unsigned short* xr = xh + (size_t)(m0 + r) * DIN_ + kt;
#pragma unroll 4
        for (int kk = 0; kk < 32; ++kk) {
            int kl = kk * 16 + j;
            float x = bf2f(xr[kl]);
#pragma unroll
            for (int c = 0; c < 16; ++c) {
                ab[c] = fmaf(x, wB[kl][c], ab[c]);
                ac[c] = fmaf(x, wC[kl][c], ac[c]);
            }
        }
    }
#pragma unroll
    for (int i = 0; i < 16; ++i) {
#pragma unroll
        for (int m = 8; m > 0; m >>= 1) {
            ab[i] += __shfl_xor(ab[i], m, 64);
            ac[i] += __shfl_xor(ac[i], m, 64);
        }
    }
    if (j == 0) {
#pragma unroll
        for (int i = 0; i < 16; ++i) {
            Bout[(size_t)(m0 + r) * 16 + i] = ab[i];
            Cout[(size_t)(m0 + r) * 16 + i] = ac[i];
        }
    }
}

// ---------------- chunked parallel scan ----------------
__global__ __launch_bounds__(256)
void scan_phase1(const __half* __restrict__ amod, const unsigned short* __restrict__ xh,
                 const float* __restrict__ Bin, const float* __restrict__ Abase,
                 float* __restrict__ P, float* __restrict__ S) {
    int d = blockIdx.x * 256 + threadIdx.x;   // 0..2047
    int c = blockIdx.y;
    int b = blockIdx.z;
    float ab[16];
#pragma unroll
    for (int n = 0; n < 16; ++n) ab[n] = sigm(Abase[n]);
    float p[16], s[16];
#pragma unroll
    for (int n = 0; n < 16; ++n) { p[n] = 1.0f; s[n] = 0.0f; }
    int t0 = c * LCHUNK;
    for (int tt = 0; tt < LCHUNK; ++tt) {
        size_t mrow = (size_t)(b * T_ + t0 + tt);
        float a = __half2float(amod[mrow * DIN_ + d]);
        float x = bf2f(xh[mrow * DIN_ + d]);
        const float4* bt4 = (const float4*)(Bin + mrow * 16);
        float4 q0 = bt4[0], q1 = bt4[1], q2 = bt4[2], q3 = bt4[3];
        float bt[16];
        bt[0]=q0.x; bt[1]=q0.y; bt[2]=q0.z; bt[3]=q0.w;
        bt[4]=q1.x; bt[5]=q1.y; bt[6]=q1.z; bt[7]=q1.w;
        bt[8]=q2.x; bt[9]=q2.y; bt[10]=q2.z; bt[11]=q2.w;
        bt[12]=q3.x; bt[13]=q3.y; bt[14]=q3.z; bt[15]=q3.w;
#pragma unroll
        for (int n = 0; n < 16; ++n) {
            float dk = a * ab[n];
            p[n] *= dk;
            s[n] = fmaf(dk, s[n], bt[n] * x);
        }
    }
    size_t base = ((size_t)(b * NCHUNK + c) << 15) + (size_t)d * 16;
    float4* P4 = (float4*)(P + base);
    float4* S4 = (float4*)(S + base);
#pragma unroll
    for (int j = 0; j < 4; ++j) {
        P4[j] = make_float4(p[4*j], p[4*j+1], p[4*j+2], p[4*j+3]);
        S4[j] = make_float4(s[4*j], s[4*j+1], s[4*j+2], s[4*j+3]);
    }
}

__global__ __launch_bounds__(256)
void scan_phase2(const float* __restrict__ P, const float* __restrict__ S,
                 float* __restrict__ H0) {
    int idx = blockIdx.x * 256 + threadIdx.x;   // 0..65535
    int b = idx >> 15;
    int dn = idx & 32767;
    float g = 0.f;
    for (int c = 0; c < NCHUNK; ++c) {
        size_t base = ((size_t)(b * NCHUNK + c) << 15) + dn;
        H0[base] = g;
        g = fmaf(P[base], g, S[base]);
    }
}

__global__ __launch_bounds__(256)
void scan_phase3(const __half* __restrict__ amod, const unsigned short* __restrict__ xh,
                 const float* __restrict__ Bin, const float* __restrict__ Cin,
                 const float* __restrict__ Abase, const float* __restrict__ H0,
                 const float* __restrict__ Dp, const unsigned short* __restrict__ szh,
                 unsigned short* __restrict__ yh) {
    int d = blockIdx.x * 256 + threadIdx.x;
    int c = blockIdx.y;
    int b = blockIdx.z;
    float ab[16];
#pragma unroll
    for (int n = 0; n < 16; ++n) ab[n] = sigm(Abase[n]);
    float h[16];
    size_t hbase = ((size_t)(b * NCHUNK + c) << 15) + (size_t)d * 16;
    const float4* H4 = (const float4*)(H0 + hbase);
#pragma unroll
    for (int j = 0; j < 4; ++j) {
        float4 t4 = H4[j];
        h[j*4] = t4.x; h[j*4+1] = t4.y; h[j*4+2] = t4.z; h[j*4+3] = t4.w;
    }
    float Dd = Dp[d];
    int t0 = c * LCHUNK;
    for (int tt = 0; tt < LCHUNK; ++tt) {
        size_t mrow = (size_t)(b * T_ + t0 + tt);
        float a = __half2float(amod[mrow * DIN_ + d]);
        float x = bf2f(xh[mrow * DIN_ + d]);
        const float4* bt4 = (const float4*)(Bin + mrow * 16);
        const float4* ct4 = (const float4*)(Cin + mrow * 16);
        float4 q0 = bt4[0], q1 = bt4[1], q2 = bt4[2], q3 = bt4[3];
        float4 r0 = ct4[0], r1 = ct4[1], r2 = ct4[2], r3 = ct4[3];
        float bt[16], ct[16];
        bt[0]=q0.x; bt[1]=q0.y; bt[2]=q0.z; bt[3]=q0.w;
        bt[4]=q1.x; bt[5]=q1.y; bt[6]=q1.z; bt[7]=q1.w;
        bt[8]=q2.x; bt[9]=q2.y; bt[10]=q2.z; bt[11]=q2.w;
        bt[12]=q3.x; bt[13]=q3.y; bt[14]=q3.z; bt[15]=q3.w;
        ct[0]=r0.x; ct[1]=r0.y; ct[2]=r0.z; ct[3]=r0.w;
        ct[4]=r1.x; ct[5]=r1.y; ct[6]=r1.z; ct[7]=r1.w;
        ct[8]=r2.x; ct[9]=r2.y; ct[10]=r2.z; ct[11]=r2.w;
        ct[12]=r3.x; ct[13]=r3.y; ct[14]=r3.z; ct[15]=r3.w;
        float y = 0.f;
#pragma unroll
        for (int n = 0; n < 16; ++n) {
            float dk = a * ab[n];
            h[n] = fmaf(dk, h[n], bt[n] * x);
            y = fmaf(h[n], ct[n], y);
        }
        float val = (y + Dd * x) * bf2f(szh[mrow * DIN_ + d]);
        yh[mrow * DIN_ + d] = f2bf(val);
    }
}

// ---------------- launch ----------------
extern "C" void kernel_launch(void* const* d_in, const int* in_sizes, int n_in,
                              void* d_out, int out_size, void* d_ws, size_t ws_size,
                              hipStream_t stream) {
    const float* x          = (const float*)d_in[0];
    const float* norm_w     = (const float*)d_in[1];
    const float* in_proj_w  = (const float*)d_in[2];
    const float* A_proj_w   = (const float*)d_in[3];
    const float* A_proj_b   = (const float*)d_in[4];
    const float* A_base     = (const float*)d_in[5];
    const float* B_proj_w   = (const float*)d_in[6];
    const float* C_proj_w   = (const float*)d_in[7];
    const float* Dp         = (const float*)d_in[8];
    const float* out_proj_w = (const float*)d_in[9];
    float* out = (float*)d_out;

    char* ws = (char*)d_ws;
    size_t off = 0;
    auto alloc = [&](size_t bytes) -> char* {
        char* p = ws + off;
        off += (bytes + 255) & ~(size_t)255;
        return p;
    };
    unsigned short* inT  = (unsigned short*)alloc((size_t)4096 * 1024 * 2);
    unsigned short* W2   = (unsigned short*)alloc((size_t)2048 * 2048 * 2);
    unsigned short* outT = (unsigned short*)alloc((size_t)1024 * 2048 * 2);
    unsigned short* xnh  = (unsigned short*)alloc((size_t)M_ * H_ * 2);
    unsigned short* xinh = (unsigned short*)alloc((size_t)M_ * DIN_ * 2);
    unsigned short* szh  = (unsigned short*)alloc((size_t)M_ * DIN_ * 2);
    __half* amod  = (__half*)alloc((size_t)M_ * DIN_ * 2);
    float* Bin    = (float*)alloc((size_t)M_ * 16 * 4);
    float* Cin    = (float*)alloc((size_t)M_ * 16 * 4);
    float* Pw     = (float*)alloc((size_t)B_ * NCHUNK * DIN_ * NS_ * 4);
    float* Sw     = (float*)alloc((size_t)B_ * NCHUNK * DIN_ * NS_ * 4);
    float* H0w    = (float*)alloc((size_t)B_ * NCHUNK * DIN_ * NS_ * 4);
    unsigned short* yh = (unsigned short*)alloc((size_t)M_ * DIN_ * 2);
    (void)ws_size;

    // fused prep: weight transposes + rmsnorm in one launch
    prep_all<<<14336, 256, 0, stream>>>(in_proj_w, A_proj_w, out_proj_w, x, norm_w,
                                        inT, W2, outT, xnh);

    // xz = xn @ in_proj  (M=4096, N=4096, K=1024): 256x256 8-phase -> 256 blocks, nt=16
    gemm8p<0, 256, 256><<<dim3(4096 / 256, M_ / 256), 512, 0, stream>>>(
        xnh, inT, 1024, nullptr, xinh, szh, nullptr, nullptr);

    // a_mod = sigmoid(x_in @ A_proj + b)  (N=2048, K=2048): 256x128 -> 256 blocks, nt=32
    gemm8p<1, 256, 128><<<dim3(2048 / 128, M_ / 256), 512, 0, stream>>>(
        xinh, W2, 2048, nullptr, nullptr, nullptr, A_proj_b, amod);

    // B_in, C_in (LDS-staged weights, 16 rows/block)
    bc_proj<<<M_ / 16, 256, 0, stream>>>(xinh, B_proj_w, C_proj_w, Bin, Cin);

    // chunked scan (NCHUNK=64)
    scan_phase1<<<dim3(DIN_ / 256, NCHUNK, B_), 256, 0, stream>>>(amod, xinh, Bin, A_base, Pw, Sw);
    scan_phase2<<<(B_ * DIN_ * NS_) / 256, 256, 0, stream>>>(Pw, Sw, H0w);
    scan_phase3<<<dim3(DIN_ / 256, NCHUNK, B_), 256, 0, stream>>>(
        amod, xinh, Bin, Cin, A_base, H0w, Dp, szh, yh);

    // out = residual + y @ out_proj  (N=1024, K=2048): 128x128 -> 256 blocks (2/CU), nt=32
    gemm8p<2, 128, 128><<<dim3(1024 / 128, M_ / 128), 512, 0, stream>>>(
        yh, outT, 2048, out, nullptr, nullptr, x, nullptr);
}